// Round 11
// baseline (160.471 us; speedup 1.0000x reference)
//
#include <hip/hip_runtime.h>
#include <hip/hip_bf16.h>
#include <math.h>

// CommNetWork pipeline v5, MI355X gfx950. fp32 in / fp32 out.
// R10 analysis: multi-dispatch is free (fixed ~75us harness overhead); the
// fused kernel is issue-starved at 1 block/CU (2 waves/SIMD) because the comm
// colsum couples 64 rows. v5 splits at the colsum:
//   prep: fp32 weights -> bf16 ws
//   K1 (512 blocks x 32 rows): obs->X1->H -> ws, + per-block partial colsums
//   K2 (512 blocks x 32 rows): GRU+V+dec, row-parallel; comm via
//       s = csum@W^T computed with broadcast-csum A-operand MFMAs.
// Fallback to the R10 single-main-kernel path if ws too small.

typedef __bf16  bf16x8 __attribute__((ext_vector_type(8)));
typedef float   f32x4  __attribute__((ext_vector_type(4)));

#define DIN 128
#define H0  256
#define SW  264   // padded LDS stride (256-wide tiles)
#define SWO 136   // padded LDS stride (128-wide obs tile)
#define LOG2E 1.44269504088896f

// ws element offsets (bf16) for converted weight matrices
#define O_WENC 0
#define O_WOBS 32768
#define O_WIH  98304
#define O_WHH  294912
#define O_WVAL 491520
#define O_WDEC 557056
#define W_TOT  573440              // bf16 elems; bytes = 1146880
#define O_H    573440              // H tile: 16384x256 bf16 = 4194304 elems
#define B_PARTS 9535488            // byte offset of partial colsums (512x256 f32)
#define WS_NEED (9535488 + 524288) // = 10059776 bytes

__device__ __forceinline__ f32x4 mfma16(bf16x8 a, bf16x8 b, f32x4 c) {
    return __builtin_amdgcn_mfma_f32_16x16x32_bf16(a, b, c, 0, 0, 0);
}
__device__ __forceinline__ float bf2f(__hip_bfloat16 x) { return __bfloat162float(x); }
__device__ __forceinline__ __hip_bfloat16 f2bf(float x) { return __float2bfloat16(x); }

__device__ __forceinline__ float fsigmoid(float x) {
    float e = __builtin_amdgcn_exp2f(-LOG2E * x);
    return __builtin_amdgcn_rcpf(1.0f + e);
}
__device__ __forceinline__ float ftanh(float x) {
    float e = __builtin_amdgcn_exp2f(2.0f * LOG2E * x);
    return 1.0f - 2.0f * __builtin_amdgcn_rcpf(1.0f + e);
}
__device__ __forceinline__ bf16x8 w8(const __hip_bfloat16* p, int idx) {
    return *(const bf16x8*)(p + idx);
}

// ---- prep: convert 6 weight matrices fp32 -> bf16 into ws ----
__global__ __launch_bounds__(256) void prep_kernel(
    const float* __restrict__ W_enc, const float* __restrict__ W_obs,
    const float* __restrict__ W_ih,  const float* __restrict__ W_hh,
    const float* __restrict__ W_val, const float* __restrict__ W_dec,
    __hip_bfloat16* __restrict__ ws)
{
    const int i = (blockIdx.x * 256 + threadIdx.x) * 8;
    if (i >= W_TOT) return;
    const float* src; int off;
    if      (i < O_WOBS) { src = W_enc; off = O_WENC; }
    else if (i < O_WIH)  { src = W_obs; off = O_WOBS; }
    else if (i < O_WHH)  { src = W_ih;  off = O_WIH;  }
    else if (i < O_WVAL) { src = W_hh;  off = O_WHH;  }
    else if (i < O_WDEC) { src = W_val; off = O_WVAL; }
    else                 { src = W_dec; off = O_WDEC; }
    const float* f = src + (i - off);
    f32x4 a = *(const f32x4*)f;
    f32x4 b = *(const f32x4*)(f + 4);
    bf16x8 v;
    #pragma unroll
    for (int j = 0; j < 4; j++) { v[j] = (__bf16)a[j]; v[j + 4] = (__bf16)b[j]; }
    *(bf16x8*)(ws + i) = v;
}

// ---- K1: obs -> X1 -> H (32 rows/block), write H + partial colsum ----
__global__ __launch_bounds__(512, 2) void k_enc(
    const __hip_bfloat16* __restrict__ ws,
    const float* __restrict__ b_enc, const float* __restrict__ b_obs,
    const float* __restrict__ obs,
    __hip_bfloat16* __restrict__ Hws, float* __restrict__ parts)
{
    __shared__ __align__(16) __hip_bfloat16 OB[32 * SWO];
    __shared__ __align__(16) __hip_bfloat16 X1[32 * SW];
    __shared__ __align__(16) __hip_bfloat16 HT[32 * SW];

    const __hip_bfloat16* W_enc = ws + O_WENC;
    const __hip_bfloat16* W_obs = ws + O_WOBS;

    const int tid  = threadIdx.x;
    const int wave = tid >> 6;
    const int lane = tid & 63;
    const int quad = lane >> 4;
    const int lc   = lane & 15;
    const int ko16 = quad * 8;
    const int R0   = blockIdx.x * 32;

    // stage obs rows R0..R0+31 (fp32 -> bf16), one 8-chunk per thread
    {
        const int r = tid >> 4;
        const int c = (tid & 15) << 3;
        const float* src = obs + (R0 + r) * DIN + c;
        f32x4 a = *(const f32x4*)src;
        f32x4 b = *(const f32x4*)(src + 4);
        bf16x8 v;
        #pragma unroll
        for (int j = 0; j < 4; j++) { v[j] = (__bf16)a[j]; v[j + 4] = (__bf16)b[j]; }
        *(bf16x8*)&OB[r * SWO + c] = v;
    }
    __syncthreads();

    // X1 = relu(obs @ W_enc^T + b_enc)
    #pragma unroll
    for (int cp = 0; cp < 2; cp++) {
        const int n = (wave + 8 * cp) * 16 + lc;
        const float bias = b_enc[n];
        f32x4 acc[2] = {};
        #pragma unroll
        for (int k0 = 0; k0 < DIN; k0 += 32) {
            const int kk = k0 + ko16;
            bf16x8 b = w8(W_enc, n * DIN + kk);
            #pragma unroll
            for (int rt = 0; rt < 2; rt++) {
                bf16x8 a = *(const bf16x8*)&OB[(rt * 16 + lc) * SWO + kk];
                acc[rt] = mfma16(a, b, acc[rt]);
            }
        }
        #pragma unroll
        for (int rt = 0; rt < 2; rt++)
            #pragma unroll
            for (int i = 0; i < 4; i++)
                X1[(rt * 16 + quad * 4 + i) * SW + n] = f2bf(fmaxf(acc[rt][i] + bias, 0.0f));
    }
    __syncthreads();

    // H = X1 @ W_obs^T + b_obs -> HT; partial colsum -> parts[block]
    #pragma unroll
    for (int cp = 0; cp < 2; cp++) {
        const int n = (wave + 8 * cp) * 16 + lc;
        const float bias = b_obs[n];
        f32x4 acc[2] = {};
        #pragma unroll 2
        for (int k0 = 0; k0 < H0; k0 += 32) {
            const int kk = k0 + ko16;
            bf16x8 b = w8(W_obs, n * H0 + kk);
            #pragma unroll
            for (int rt = 0; rt < 2; rt++) {
                bf16x8 a = *(const bf16x8*)&X1[(rt * 16 + lc) * SW + kk];
                acc[rt] = mfma16(a, b, acc[rt]);
            }
        }
        float colp = 0.0f;
        #pragma unroll
        for (int rt = 0; rt < 2; rt++)
            #pragma unroll
            for (int i = 0; i < 4; i++) {
                const float v = acc[rt][i] + bias;
                HT[(rt * 16 + quad * 4 + i) * SW + n] = f2bf(v);
                colp += v;
            }
        colp += __shfl_xor(colp, 16);
        colp += __shfl_xor(colp, 32);
        if (quad == 0) parts[blockIdx.x * 256 + n] = colp;
    }
    __syncthreads();

    // HT -> Hws (coalesced b128 stores)
    {
        const int r = tid >> 4;
        const int c = (tid << 4) & 255;
        *(bf16x8*)&Hws[(R0 + r) * 256 + c]     = *(const bf16x8*)&HT[r * SW + c];
        *(bf16x8*)&Hws[(R0 + r) * 256 + c + 8] = *(const bf16x8*)&HT[r * SW + c + 8];
    }
}

// ---- K2: GRU + value + decode, row-parallel (32 rows/block) ----
__global__ __launch_bounds__(512, 2) void k_gru(
    const __hip_bfloat16* __restrict__ ws,
    const float* __restrict__ b_ih,  const float* __restrict__ b_hh,
    const float* __restrict__ b_val, const float* __restrict__ b_dec,
    const __hip_bfloat16* __restrict__ Hws, const float* __restrict__ parts,
    float* __restrict__ out)
{
    __shared__ __align__(16) __hip_bfloat16 HT[32 * SW];   // H, then V
    __shared__ __align__(16) __hip_bfloat16 HP[32 * SW];   // h'
    __shared__ __align__(16) __hip_bfloat16 CS[256];       // csum(H) of batch, bf16

    const __hip_bfloat16* W_ih  = ws + O_WIH;
    const __hip_bfloat16* W_hh  = ws + O_WHH;
    const __hip_bfloat16* W_val = ws + O_WVAL;
    const __hip_bfloat16* W_dec = ws + O_WDEC;

    const int tid  = threadIdx.x;
    const int wave = tid >> 6;
    const int lane = tid & 63;
    const int quad = lane >> 4;
    const int lc   = lane & 15;
    const int ko16 = quad * 8;
    const int R0   = blockIdx.x * 32;
    const int pb   = blockIdx.x & ~1;   // the two K1 blocks of this batch

    // stage H rows + csum
    {
        const int r = tid >> 4;
        const int c = (tid << 4) & 255;
        *(bf16x8*)&HT[r * SW + c]     = *(const bf16x8*)&Hws[(R0 + r) * 256 + c];
        *(bf16x8*)&HT[r * SW + c + 8] = *(const bf16x8*)&Hws[(R0 + r) * 256 + c + 8];
        if (tid < 256)
            CS[tid] = f2bf(parts[pb * 256 + tid] + parts[(pb + 1) * 256 + tid]);
    }
    __syncthreads();

    // GRU: G = H@W^T per stream; gi = (s - Gi)/64 + b_ih, s = csum@W_ih^T
    // computed via broadcast-csum A-operand (all A rows = csum -> all D rows = s).
    #pragma unroll
    for (int cp = 0; cp < 2; cp++) {
        const int n = (wave + 8 * cp) * 16 + lc;
        const float bir = b_ih[n], biz = b_ih[n + 256], bin = b_ih[n + 512];
        const float bhr = b_hh[n], bhz = b_hh[n + 256], bhn = b_hh[n + 512];
        f32x4 gir[2] = {}, giz[2] = {}, gin[2] = {};
        f32x4 ghr[2] = {}, ghz[2] = {}, ghn[2] = {};
        f32x4 sr = {}, sz = {}, sn = {};
        #pragma unroll 2
        for (int k0 = 0; k0 < H0; k0 += 32) {
            const int kk = k0 + ko16;
            bf16x8 csA = *(const bf16x8*)&CS[kk];   // broadcast within quad
            bf16x8 bir8 = w8(W_ih, (n      ) * H0 + kk);
            bf16x8 biz8 = w8(W_ih, (n + 256) * H0 + kk);
            bf16x8 bin8 = w8(W_ih, (n + 512) * H0 + kk);
            bf16x8 bhr8 = w8(W_hh, (n      ) * H0 + kk);
            bf16x8 bhz8 = w8(W_hh, (n + 256) * H0 + kk);
            bf16x8 bhn8 = w8(W_hh, (n + 512) * H0 + kk);
            sr = mfma16(csA, bir8, sr);
            sz = mfma16(csA, biz8, sz);
            sn = mfma16(csA, bin8, sn);
            #pragma unroll
            for (int rt = 0; rt < 2; rt++) {
                bf16x8 aH = *(const bf16x8*)&HT[(rt * 16 + lc) * SW + kk];
                gir[rt] = mfma16(aH, bir8, gir[rt]);
                giz[rt] = mfma16(aH, biz8, giz[rt]);
                gin[rt] = mfma16(aH, bin8, gin[rt]);
                ghr[rt] = mfma16(aH, bhr8, ghr[rt]);
                ghz[rt] = mfma16(aH, bhz8, ghz[rt]);
                ghn[rt] = mfma16(aH, bhn8, ghn[rt]);
            }
        }
        const float s_r = sr[0], s_z = sz[0], s_n = sn[0];
        #pragma unroll
        for (int rt = 0; rt < 2; rt++)
            #pragma unroll
            for (int i = 0; i < 4; i++) {
                const int row = rt * 16 + quad * 4 + i;
                const float gi_r = (s_r - gir[rt][i]) * (1.0f / 64.0f) + bir;
                const float gi_z = (s_z - giz[rt][i]) * (1.0f / 64.0f) + biz;
                const float gi_n = (s_n - gin[rt][i]) * (1.0f / 64.0f) + bin;
                const float r  = fsigmoid(gi_r + ghr[rt][i] + bhr);
                const float z  = fsigmoid(gi_z + ghz[rt][i] + bhz);
                const float nn = ftanh(gi_n + r * (ghn[rt][i] + bhn));
                const float h  = bf2f(HT[row * SW + n]);
                HP[row * SW + n] = f2bf((1.0f - z) * nn + z * h);
            }
    }
    __syncthreads();

    // V = h' @ W_val^T + b_val -> HT (H dead)
    #pragma unroll
    for (int cp = 0; cp < 2; cp++) {
        const int n = (wave + 8 * cp) * 16 + lc;
        const float bias = b_val[n];
        f32x4 acc[2] = {};
        #pragma unroll 2
        for (int k0 = 0; k0 < H0; k0 += 32) {
            const int kk = k0 + ko16;
            bf16x8 b = w8(W_val, n * H0 + kk);
            #pragma unroll
            for (int rt = 0; rt < 2; rt++) {
                bf16x8 a = *(const bf16x8*)&HP[(rt * 16 + lc) * SW + kk];
                acc[rt] = mfma16(a, b, acc[rt]);
            }
        }
        #pragma unroll
        for (int rt = 0; rt < 2; rt++)
            #pragma unroll
            for (int i = 0; i < 4; i++)
                HT[(rt * 16 + quad * 4 + i) * SW + n] = f2bf(acc[rt][i] + bias);
    }
    __syncthreads();

    // OUT = V @ W_dec^T + b_dec
    {
        const int ct = wave & 3;           // 4 col-tiles (H2=64)
        const int rt = wave >> 2;          // 2 row-tiles of 16
        const int n  = ct * 16 + lc;
        const float bias = b_dec[n];
        f32x4 acc = {};
        #pragma unroll 2
        for (int k0 = 0; k0 < H0; k0 += 32) {
            const int kk = k0 + ko16;
            bf16x8 b = w8(W_dec, n * H0 + kk);
            bf16x8 a = *(const bf16x8*)&HT[(rt * 16 + lc) * SW + kk];
            acc = mfma16(a, b, acc);
        }
        #pragma unroll
        for (int i = 0; i < 4; i++)
            out[(R0 + rt * 16 + quad * 4 + i) * 64 + n] = acc[i] + bias;
    }
}

// ================= fallback: R10 fused kernel (ws too small) =================
__global__ __launch_bounds__(512, 2) void commnet_fused(
    const __hip_bfloat16* __restrict__ ws,
    const float* __restrict__ b_enc, const float* __restrict__ b_obs,
    const float* __restrict__ b_ih,  const float* __restrict__ b_hh,
    const float* __restrict__ b_val, const float* __restrict__ b_dec,
    const float* __restrict__ obs,   float* __restrict__ out)
{
    __shared__ __align__(16) __hip_bfloat16 T0[64 * SW];
    __shared__ __align__(16) __hip_bfloat16 T1[64 * SW];

    const __hip_bfloat16* W_enc = ws + O_WENC;
    const __hip_bfloat16* W_obs = ws + O_WOBS;
    const __hip_bfloat16* W_ih  = ws + O_WIH;
    const __hip_bfloat16* W_hh  = ws + O_WHH;
    const __hip_bfloat16* W_val = ws + O_WVAL;
    const __hip_bfloat16* W_dec = ws + O_WDEC;

    const int tid  = threadIdx.x;
    const int wave = tid >> 6;
    const int lane = tid & 63;
    const int quad = lane >> 4;
    const int lc   = lane & 15;
    const int row0 = blockIdx.x * 64;
    const int ko16 = quad * 8;

    for (int i = tid; i < 64 * DIN / 8; i += 512) {
        const int r = i >> 4;
        const int c = (i & 15) << 3;
        const float* src = obs + (row0 + r) * DIN + c;
        f32x4 a = *(const f32x4*)src;
        f32x4 b = *(const f32x4*)(src + 4);
        bf16x8 v;
        #pragma unroll
        for (int j = 0; j < 4; j++) { v[j] = (__bf16)a[j]; v[j + 4] = (__bf16)b[j]; }
        *(bf16x8*)&T1[r * SWO + c] = v;
    }
    __syncthreads();

    #pragma unroll
    for (int cp = 0; cp < 2; cp++) {
        const int n = (wave + 8 * cp) * 16 + lc;
        const float bias = b_enc[n];
        f32x4 acc[4] = {};
        #pragma unroll
        for (int k0 = 0; k0 < DIN; k0 += 32) {
            const int kk = k0 + ko16;
            bf16x8 b = w8(W_enc, n * DIN + kk);
            #pragma unroll
            for (int rt = 0; rt < 4; rt++) {
                bf16x8 a = *(const bf16x8*)&T1[(rt * 16 + lc) * SWO + kk];
                acc[rt] = mfma16(a, b, acc[rt]);
            }
        }
        #pragma unroll
        for (int rt = 0; rt < 4; rt++)
            #pragma unroll
            for (int i = 0; i < 4; i++)
                T0[(rt * 16 + quad * 4 + i) * SW + n] = f2bf(fmaxf(acc[rt][i] + bias, 0.0f));
    }
    __syncthreads();

    #pragma unroll
    for (int cp = 0; cp < 2; cp++) {
        const int n = (wave + 8 * cp) * 16 + lc;
        const float bias = b_obs[n];
        f32x4 acc[4] = {};
        #pragma unroll 2
        for (int k0 = 0; k0 < H0; k0 += 32) {
            const int kk = k0 + ko16;
            bf16x8 b = w8(W_obs, n * H0 + kk);
            #pragma unroll
            for (int rt = 0; rt < 4; rt++) {
                bf16x8 a = *(const bf16x8*)&T0[(rt * 16 + lc) * SW + kk];
                acc[rt] = mfma16(a, b, acc[rt]);
            }
        }
        #pragma unroll
        for (int rt = 0; rt < 4; rt++)
            #pragma unroll
            for (int i = 0; i < 4; i++)
                T1[(rt * 16 + quad * 4 + i) * SW + n] = f2bf(acc[rt][i] + bias);
    }
    __syncthreads();

    #pragma unroll
    for (int cp = 0; cp < 2; cp++) {
        const int n = (wave + 8 * cp) * 16 + lc;
        const float bir = b_ih[n], biz = b_ih[n + 256], bin = b_ih[n + 512];
        const float bhr = b_hh[n], bhz = b_hh[n + 256], bhn = b_hh[n + 512];
        f32x4 gir[4] = {}, giz[4] = {}, gin[4] = {};
        f32x4 ghr[4] = {}, ghz[4] = {}, ghn[4] = {};
        #pragma unroll 2
        for (int k0 = 0; k0 < H0; k0 += 32) {
            const int kk = k0 + ko16;
            bf16x8 bir8 = w8(W_ih, (n      ) * H0 + kk);
            bf16x8 biz8 = w8(W_ih, (n + 256) * H0 + kk);
            bf16x8 bin8 = w8(W_ih, (n + 512) * H0 + kk);
            bf16x8 bhr8 = w8(W_hh, (n      ) * H0 + kk);
            bf16x8 bhz8 = w8(W_hh, (n + 256) * H0 + kk);
            bf16x8 bhn8 = w8(W_hh, (n + 512) * H0 + kk);
            #pragma unroll
            for (int rt = 0; rt < 4; rt++) {
                bf16x8 aH = *(const bf16x8*)&T1[(rt * 16 + lc) * SW + kk];
                gir[rt] = mfma16(aH, bir8, gir[rt]);
                giz[rt] = mfma16(aH, biz8, giz[rt]);
                gin[rt] = mfma16(aH, bin8, gin[rt]);
                ghr[rt] = mfma16(aH, bhr8, ghr[rt]);
                ghz[rt] = mfma16(aH, bhz8, ghz[rt]);
                ghn[rt] = mfma16(aH, bhn8, ghn[rt]);
            }
        }
        float Sr = 0.0f, Sz = 0.0f, Sn = 0.0f;
        #pragma unroll
        for (int rt = 0; rt < 4; rt++)
            #pragma unroll
            for (int i = 0; i < 4; i++) {
                Sr += gir[rt][i]; Sz += giz[rt][i]; Sn += gin[rt][i];
            }
        Sr += __shfl_xor(Sr, 16); Sr += __shfl_xor(Sr, 32);
        Sz += __shfl_xor(Sz, 16); Sz += __shfl_xor(Sz, 32);
        Sn += __shfl_xor(Sn, 16); Sn += __shfl_xor(Sn, 32);
        #pragma unroll
        for (int rt = 0; rt < 4; rt++)
            #pragma unroll
            for (int i = 0; i < 4; i++) {
                const int row = rt * 16 + quad * 4 + i;
                const float gi_r = (Sr - gir[rt][i]) * (1.0f / 64.0f) + bir;
                const float gi_z = (Sz - giz[rt][i]) * (1.0f / 64.0f) + biz;
                const float gi_n = (Sn - gin[rt][i]) * (1.0f / 64.0f) + bin;
                const float r  = fsigmoid(gi_r + ghr[rt][i] + bhr);
                const float z  = fsigmoid(gi_z + ghz[rt][i] + bhz);
                const float nn = ftanh(gi_n + r * (ghn[rt][i] + bhn));
                const float h  = bf2f(T1[row * SW + n]);
                T0[row * SW + n] = f2bf((1.0f - z) * nn + z * h);
            }
    }
    __syncthreads();

    #pragma unroll
    for (int cp = 0; cp < 2; cp++) {
        const int n = (wave + 8 * cp) * 16 + lc;
        const float bias = b_val[n];
        f32x4 acc[4] = {};
        #pragma unroll 2
        for (int k0 = 0; k0 < H0; k0 += 32) {
            const int kk = k0 + ko16;
            bf16x8 b = w8(W_val, n * H0 + kk);
            #pragma unroll
            for (int rt = 0; rt < 4; rt++) {
                bf16x8 a = *(const bf16x8*)&T0[(rt * 16 + lc) * SW + kk];
                acc[rt] = mfma16(a, b, acc[rt]);
            }
        }
        #pragma unroll
        for (int rt = 0; rt < 4; rt++)
            #pragma unroll
            for (int i = 0; i < 4; i++)
                T1[(rt * 16 + quad * 4 + i) * SW + n] = f2bf(acc[rt][i] + bias);
    }
    __syncthreads();

    {
        const int ct  = wave & 3;
        const int rtb = (wave >> 2) * 2;
        const int n   = ct * 16 + lc;
        const float bias = b_dec[n];
        f32x4 acc[2] = {};
        #pragma unroll 2
        for (int k0 = 0; k0 < H0; k0 += 32) {
            const int kk = k0 + ko16;
            bf16x8 b = w8(W_dec, n * H0 + kk);
            #pragma unroll
            for (int j = 0; j < 2; j++) {
                bf16x8 a = *(const bf16x8*)&T1[((rtb + j) * 16 + lc) * SW + kk];
                acc[j] = mfma16(a, b, acc[j]);
            }
        }
        #pragma unroll
        for (int j = 0; j < 2; j++)
            #pragma unroll
            for (int i = 0; i < 4; i++) {
                const int row = (rtb + j) * 16 + quad * 4 + i;
                out[(row0 + row) * 64 + n] = acc[j][i] + bias;
            }
    }
}

extern "C" void kernel_launch(void* const* d_in, const int* in_sizes, int n_in,
                              void* d_out, int out_size, void* d_ws, size_t ws_size,
                              hipStream_t stream) {
    (void)in_sizes; (void)n_in; (void)out_size;
    const float* obs   = (const float*)d_in[0];
    const float* W_enc = (const float*)d_in[1];  const float* b_enc = (const float*)d_in[2];
    const float* W_obs = (const float*)d_in[3];  const float* b_obs = (const float*)d_in[4];
    const float* W_ih  = (const float*)d_in[5];  const float* b_ih  = (const float*)d_in[6];
    const float* W_hh  = (const float*)d_in[7];  const float* b_hh  = (const float*)d_in[8];
    const float* W_val = (const float*)d_in[9];  const float* b_val = (const float*)d_in[10];
    const float* W_dec = (const float*)d_in[11]; const float* b_dec = (const float*)d_in[12];
    float* out = (float*)d_out;
    __hip_bfloat16* ws = (__hip_bfloat16*)d_ws;

    prep_kernel<<<280, 256, 0, stream>>>(W_enc, W_obs, W_ih, W_hh, W_val, W_dec, ws);

    if (ws_size >= (size_t)WS_NEED) {
        __hip_bfloat16* Hws  = ws + O_H;
        float* parts = (float*)((char*)d_ws + B_PARTS);
        k_enc<<<512, 512, 0, stream>>>(ws, b_enc, b_obs, obs, Hws, parts);
        k_gru<<<512, 512, 0, stream>>>(ws, b_ih, b_hh, b_val, b_dec, Hws, parts, out);
    } else {
        commnet_fused<<<256, 512, 0, stream>>>(
            ws, b_enc, b_obs, b_ih, b_hh, b_val, b_dec, obs, out);
    }
}

// Round 12
// 154.363 us; speedup vs baseline: 1.0396x; 1.0396x over previous
//
#include <hip/hip_runtime.h>
#include <hip/hip_bf16.h>
#include <math.h>

// CommNetWork v6, MI355X gfx950. fp32 in / fp32 out.
// R11 lesson: fused 1-block/batch shape is right; exposed per-wave L2 weight
// latency is the bottleneck. v6 = fused kernel with LDS-staged DOUBLE-BUFFERED
// weights (AITER-style): cooperative bulk global->reg->LDS staging of 32KB
// chunks overlapped with MFMA compute that reads weights only from LDS.
// Activations: XOR-swizzled 32KB tiles (R3-verified). LDS = 32+32+64 = 128KB.

typedef __bf16  bf16x8 __attribute__((ext_vector_type(8)));
typedef float   f32x4  __attribute__((ext_vector_type(4)));

#define DIN 128
#define H0  256
#define LOG2E 1.44269504088896f

#define O_WENC 0
#define O_WOBS 32768
#define O_WIH  98304
#define O_WHH  294912
#define O_WVAL 491520
#define O_WDEC 557056
#define W_TOT  573440   // bf16 elems; ws bytes needed = 1146880

__device__ __forceinline__ f32x4 mfma16(bf16x8 a, bf16x8 b, f32x4 c) {
    return __builtin_amdgcn_mfma_f32_16x16x32_bf16(a, b, c, 0, 0, 0);
}
__device__ __forceinline__ float bf2f(__hip_bfloat16 x) { return __bfloat162float(x); }
__device__ __forceinline__ __hip_bfloat16 f2bf(float x) { return __float2bfloat16(x); }
__device__ __forceinline__ float fsigmoid(float x) {
    float e = __builtin_amdgcn_exp2f(-LOG2E * x);
    return __builtin_amdgcn_rcpf(1.0f + e);
}
__device__ __forceinline__ float ftanh(float x) {
    float e = __builtin_amdgcn_exp2f(2.0f * LOG2E * x);
    return 1.0f - 2.0f * __builtin_amdgcn_rcpf(1.0f + e);
}
__device__ __forceinline__ bf16x8 w8(const __hip_bfloat16* p, int idx) {
    return *(const bf16x8*)(p + idx);
}

// XOR-swizzled activation tiles (compute-correct per R3)
__device__ __forceinline__ int tadr(int r, int k) {
    return (r << 8) + ((((k >> 3) ^ r) & 31) << 3) + (k & 7);
}
__device__ __forceinline__ int oadr(int r, int k) {
    return (r << 7) + ((((k >> 3) ^ r) & 15) << 3) + (k & 7);
}

struct St4 { bf16x8 v[4]; };

// ---- square weight chunk [256 n][64 k] = 32KB, swizzled by n&7 ----
__device__ __forceinline__ St4 ld_sq(const __hip_bfloat16* src, int K, int kb, int tid) {
    St4 s;
    #pragma unroll
    for (int j = 0; j < 4; j++) {
        const int u = tid + j * 512, n = u >> 3, c = u & 7;
        s.v[j] = w8(src, n * K + kb * 64 + c * 8);
    }
    return s;
}
__device__ __forceinline__ void st_sq(__hip_bfloat16* dst, const St4& s, int tid) {
    #pragma unroll
    for (int j = 0; j < 4; j++) {
        const int u = tid + j * 512, n = u >> 3, c = u & 7;
        *(bf16x8*)&dst[n * 64 + ((c ^ (n & 7)) << 3)] = s.v[j];
    }
}
__device__ __forceinline__ bf16x8 rd_sq(const __hip_bfloat16* wb, int n, int kw) {
    return *(const bf16x8*)&wb[n * 64 + ((((kw >> 3) ^ (n & 7)) & 7) << 3)];
}

// ---- GRU pair chunk: slab0 = i-gate p, slab1 = h-gate p; each [128 n][64 k] ----
__device__ __forceinline__ St4 ld_gr(const __hip_bfloat16* Wih, const __hip_bfloat16* Whh,
                                     int p, int cp, int kb, int tid) {
    St4 s;
    #pragma unroll
    for (int j = 0; j < 4; j++) {
        const int u = tid + j * 512, g2 = u >> 10, rem = u & 1023, nl = rem >> 3, c = rem & 7;
        const __hip_bfloat16* m = g2 ? Whh : Wih;
        s.v[j] = w8(m, (p * 256 + cp * 128 + nl) * 256 + kb * 64 + c * 8);
    }
    return s;
}
__device__ __forceinline__ void st_gr(__hip_bfloat16* dst, const St4& s, int tid) {
    #pragma unroll
    for (int j = 0; j < 4; j++) {
        const int u = tid + j * 512, g2 = u >> 10, rem = u & 1023, nl = rem >> 3, c = rem & 7;
        *(bf16x8*)&dst[g2 * 8192 + nl * 64 + ((c ^ (nl & 7)) << 3)] = s.v[j];
    }
}
__device__ __forceinline__ bf16x8 rd_gr(const __hip_bfloat16* wb, int g2, int nl, int kw) {
    return *(const bf16x8*)&wb[g2 * 8192 + nl * 64 + ((((kw >> 3) ^ (nl & 7)) & 7) << 3)];
}

// ---- prep: fp32 weights -> bf16 ws ----
__global__ __launch_bounds__(256) void prep_kernel(
    const float* __restrict__ W_enc, const float* __restrict__ W_obs,
    const float* __restrict__ W_ih,  const float* __restrict__ W_hh,
    const float* __restrict__ W_val, const float* __restrict__ W_dec,
    __hip_bfloat16* __restrict__ ws)
{
    const int i = (blockIdx.x * 256 + threadIdx.x) * 8;
    if (i >= W_TOT) return;
    const float* src; int off;
    if      (i < O_WOBS) { src = W_enc; off = O_WENC; }
    else if (i < O_WIH)  { src = W_obs; off = O_WOBS; }
    else if (i < O_WHH)  { src = W_ih;  off = O_WIH;  }
    else if (i < O_WVAL) { src = W_hh;  off = O_WHH;  }
    else if (i < O_WDEC) { src = W_val; off = O_WVAL; }
    else                 { src = W_dec; off = O_WDEC; }
    const float* f = src + (i - off);
    f32x4 a = *(const f32x4*)f;
    f32x4 b = *(const f32x4*)(f + 4);
    bf16x8 v;
    #pragma unroll
    for (int j = 0; j < 4; j++) { v[j] = (__bf16)a[j]; v[j + 4] = (__bf16)b[j]; }
    *(bf16x8*)(ws + i) = v;
}

__global__ __launch_bounds__(512, 2) void commnet_v6(
    const __hip_bfloat16* __restrict__ ws,
    const float* __restrict__ b_enc, const float* __restrict__ b_obs,
    const float* __restrict__ b_ih,  const float* __restrict__ b_hh,
    const float* __restrict__ b_val, const float* __restrict__ b_dec,
    const float* __restrict__ obs,   float* __restrict__ out)
{
    __shared__ __align__(16) __hip_bfloat16 T0[16384];   // X1 -> h'
    __shared__ __align__(16) __hip_bfloat16 T1[16384];   // obs -> H -> V
    __shared__ __align__(16) __hip_bfloat16 WBb[32768];  // 2 x 32KB weight buffers

    const __hip_bfloat16* W_enc = ws + O_WENC;
    const __hip_bfloat16* W_obs = ws + O_WOBS;
    const __hip_bfloat16* W_ih  = ws + O_WIH;
    const __hip_bfloat16* W_hh  = ws + O_WHH;
    const __hip_bfloat16* W_val = ws + O_WVAL;
    const __hip_bfloat16* W_dec = ws + O_WDEC;

    const int tid  = threadIdx.x;
    const int wave = tid >> 6;
    const int lane = tid & 63;
    const int quad = lane >> 4;
    const int lc   = lane & 15;
    const int row0 = blockIdx.x * 64;
    const int ko16 = quad * 8;
    const int n0   = wave * 16 + lc;     // cp0 column
    const int n1   = n0 + 128;           // cp1 column

    // ---- A) stage obs -> T1 (swizzled) + prime enc chunk kb0 -> WB0 ----
    {
        #pragma unroll
        for (int j = 0; j < 2; j++) {
            const int u = tid + j * 512;
            const int r = u >> 4, c = (u & 15) << 3;
            const float* src = obs + (row0 + r) * DIN + c;
            f32x4 a = *(const f32x4*)src;
            f32x4 b = *(const f32x4*)(src + 4);
            bf16x8 v;
            #pragma unroll
            for (int q = 0; q < 4; q++) { v[q] = (__bf16)a[q]; v[q + 4] = (__bf16)b[q]; }
            *(bf16x8*)&T1[oadr(r, c)] = v;
        }
        St4 s0 = ld_sq(W_enc, DIN, 0, tid);
        st_sq(WBb, s0, tid);
    }
    __syncthreads();

    // ---- B) ENC: X1 = relu(obs @ W_enc^T + b) -> T0 (2 chunks) ----
    {
        f32x4 acc[2][4] = {};
        #pragma unroll
        for (int kb = 0; kb < 2; kb++) {
            St4 nx = (kb == 0) ? ld_sq(W_enc, DIN, 1, tid) : ld_sq(W_obs, H0, 0, tid);
            const __hip_bfloat16* wb = WBb + (kb & 1) * 16384;
            #pragma unroll
            for (int ki = 0; ki < 2; ki++) {
                const int kt = kb * 64 + ki * 32 + ko16;
                const int kw = ki * 32 + ko16;
                bf16x8 a[4];
                #pragma unroll
                for (int rt = 0; rt < 4; rt++) a[rt] = *(const bf16x8*)&T1[oadr(rt * 16 + lc, kt)];
                bf16x8 b0 = rd_sq(wb, n0, kw);
                bf16x8 b1 = rd_sq(wb, n1, kw);
                #pragma unroll
                for (int rt = 0; rt < 4; rt++) {
                    acc[0][rt] = mfma16(a[rt], b0, acc[0][rt]);
                    acc[1][rt] = mfma16(a[rt], b1, acc[1][rt]);
                }
            }
            st_sq(WBb + ((kb + 1) & 1) * 16384, nx, tid);
            __syncthreads();
        }
        #pragma unroll
        for (int cp = 0; cp < 2; cp++) {
            const int n = cp ? n1 : n0;
            const float bias = b_enc[n];
            #pragma unroll
            for (int rt = 0; rt < 4; rt++)
                #pragma unroll
                for (int i = 0; i < 4; i++)
                    T0[tadr(rt * 16 + quad * 4 + i, n)] = f2bf(fmaxf(acc[cp][rt][i] + bias, 0.0f));
        }
    }
    __syncthreads();

    // ---- C) OBS: H = X1 @ W_obs^T + b -> T1 (4 chunks) ----
    {
        f32x4 acc[2][4] = {};
        #pragma unroll
        for (int kb = 0; kb < 4; kb++) {
            St4 nx;
            if (kb < 3) nx = ld_sq(W_obs, H0, kb + 1, tid);
            else        nx = ld_gr(W_ih, W_hh, 0, 0, 0, tid);
            const __hip_bfloat16* wb = WBb + (kb & 1) * 16384;
            #pragma unroll
            for (int ki = 0; ki < 2; ki++) {
                const int kt = kb * 64 + ki * 32 + ko16;
                const int kw = ki * 32 + ko16;
                bf16x8 a[4];
                #pragma unroll
                for (int rt = 0; rt < 4; rt++) a[rt] = *(const bf16x8*)&T0[tadr(rt * 16 + lc, kt)];
                bf16x8 b0 = rd_sq(wb, n0, kw);
                bf16x8 b1 = rd_sq(wb, n1, kw);
                #pragma unroll
                for (int rt = 0; rt < 4; rt++) {
                    acc[0][rt] = mfma16(a[rt], b0, acc[0][rt]);
                    acc[1][rt] = mfma16(a[rt], b1, acc[1][rt]);
                }
            }
            if (kb < 3) st_sq(WBb + ((kb + 1) & 1) * 16384, nx, tid);
            else        st_gr(WBb + ((kb + 1) & 1) * 16384, nx, tid);
            __syncthreads();
        }
        #pragma unroll
        for (int cp = 0; cp < 2; cp++) {
            const int n = cp ? n1 : n0;
            const float bias = b_obs[n];
            #pragma unroll
            for (int rt = 0; rt < 4; rt++)
                #pragma unroll
                for (int i = 0; i < 4; i++)
                    T1[tadr(rt * 16 + quad * 4 + i, n)] = f2bf(acc[cp][rt][i] + bias);
        }
    }
    __syncthreads();

    // ---- D) GRU with folded comm: 24 pair-chunks (2 cp x 4 kb x 3 pairs) ----
    // acc[0..2] = i-gates r,z,n; acc[3..5] = h-gates r,z,n.
    {
        int g = 0;
        #pragma unroll
        for (int cp = 0; cp < 2; cp++) {
            f32x4 acc[6][4] = {};
            #pragma unroll
            for (int kb = 0; kb < 4; kb++) {
                #pragma unroll
                for (int p = 0; p < 3; p++) {
                    // next chunk coords
                    int pn = p + 1, kbn = kb, cpn = cp;
                    if (pn == 3) { pn = 0; kbn++; if (kbn == 4) { kbn = 0; cpn++; } }
                    St4 nx;
                    if (cpn < 2) nx = ld_gr(W_ih, W_hh, pn, cpn, kbn, tid);
                    else         nx = ld_sq(W_val, H0, 0, tid);
                    const __hip_bfloat16* wb = WBb + (g & 1) * 16384;
                    #pragma unroll
                    for (int ki = 0; ki < 2; ki++) {
                        const int kt = kb * 64 + ki * 32 + ko16;
                        const int kw = ki * 32 + ko16;
                        bf16x8 a[4];
                        #pragma unroll
                        for (int rt = 0; rt < 4; rt++)
                            a[rt] = *(const bf16x8*)&T1[tadr(rt * 16 + lc, kt)];
                        bf16x8 bi = rd_gr(wb, 0, n0, kw);
                        bf16x8 bh = rd_gr(wb, 1, n0, kw);
                        #pragma unroll
                        for (int rt = 0; rt < 4; rt++) {
                            acc[p][rt]     = mfma16(a[rt], bi, acc[p][rt]);
                            acc[3 + p][rt] = mfma16(a[rt], bh, acc[3 + p][rt]);
                        }
                    }
                    if (cpn < 2) st_gr(WBb + ((g + 1) & 1) * 16384, nx, tid);
                    else         st_sq(WBb + ((g + 1) & 1) * 16384, nx, tid);
                    __syncthreads();
                    g++;
                }
            }
            // cp epilogue: colsum-fold + gates, h' -> T0
            {
                const int n = cp ? n1 : n0;
                const float bir = b_ih[n], biz = b_ih[n + 256], bin = b_ih[n + 512];
                const float bhr = b_hh[n], bhz = b_hh[n + 256], bhn = b_hh[n + 512];
                float Sr = 0.0f, Sz = 0.0f, Sn = 0.0f;
                #pragma unroll
                for (int rt = 0; rt < 4; rt++)
                    #pragma unroll
                    for (int i = 0; i < 4; i++) {
                        Sr += acc[0][rt][i]; Sz += acc[1][rt][i]; Sn += acc[2][rt][i];
                    }
                Sr += __shfl_xor(Sr, 16); Sr += __shfl_xor(Sr, 32);
                Sz += __shfl_xor(Sz, 16); Sz += __shfl_xor(Sz, 32);
                Sn += __shfl_xor(Sn, 16); Sn += __shfl_xor(Sn, 32);
                #pragma unroll
                for (int rt = 0; rt < 4; rt++)
                    #pragma unroll
                    for (int i = 0; i < 4; i++) {
                        const int row = rt * 16 + quad * 4 + i;
                        const float gi_r = (Sr - acc[0][rt][i]) * (1.0f / 64.0f) + bir;
                        const float gi_z = (Sz - acc[1][rt][i]) * (1.0f / 64.0f) + biz;
                        const float gi_n = (Sn - acc[2][rt][i]) * (1.0f / 64.0f) + bin;
                        const float r  = fsigmoid(gi_r + acc[3][rt][i] + bhr);
                        const float z  = fsigmoid(gi_z + acc[4][rt][i] + bhz);
                        const float nn = ftanh(gi_n + r * (acc[5][rt][i] + bhn));
                        const float h  = bf2f(T1[tadr(row, n)]);
                        T0[tadr(row, n)] = f2bf((1.0f - z) * nn + z * h);
                    }
            }
        }
    }
    __syncthreads();

    // ---- E) VAL: V = h' @ W_val^T + b -> T1 (4 chunks) ----
    {
        f32x4 acc[2][4] = {};
        #pragma unroll
        for (int kb = 0; kb < 4; kb++) {
            St4 nx;
            const bool hn = kb < 3;
            if (hn) nx = ld_sq(W_val, H0, kb + 1, tid);
            const __hip_bfloat16* wb = WBb + (kb & 1) * 16384;
            #pragma unroll
            for (int ki = 0; ki < 2; ki++) {
                const int kt = kb * 64 + ki * 32 + ko16;
                const int kw = ki * 32 + ko16;
                bf16x8 a[4];
                #pragma unroll
                for (int rt = 0; rt < 4; rt++) a[rt] = *(const bf16x8*)&T0[tadr(rt * 16 + lc, kt)];
                bf16x8 b0 = rd_sq(wb, n0, kw);
                bf16x8 b1 = rd_sq(wb, n1, kw);
                #pragma unroll
                for (int rt = 0; rt < 4; rt++) {
                    acc[0][rt] = mfma16(a[rt], b0, acc[0][rt]);
                    acc[1][rt] = mfma16(a[rt], b1, acc[1][rt]);
                }
            }
            if (hn) st_sq(WBb + ((kb + 1) & 1) * 16384, nx, tid);
            __syncthreads();
        }
        #pragma unroll
        for (int cp = 0; cp < 2; cp++) {
            const int n = cp ? n1 : n0;
            const float bias = b_val[n];
            #pragma unroll
            for (int rt = 0; rt < 4; rt++)
                #pragma unroll
                for (int i = 0; i < 4; i++)
                    T1[tadr(rt * 16 + quad * 4 + i, n)] = f2bf(acc[cp][rt][i] + bias);
        }
    }
    __syncthreads();

    // ---- F) DEC: OUT = V @ W_dec^T + b (direct from ws, 32KB) ----
    {
        const int ct  = wave & 3;
        const int rtb = (wave >> 2) * 2;
        const int nd  = ct * 16 + lc;
        const float bias = b_dec[nd];
        f32x4 acc[2] = {};
        #pragma unroll
        for (int k0 = 0; k0 < H0; k0 += 32) {
            const int kk = k0 + ko16;
            bf16x8 b = w8(W_dec, nd * H0 + kk);
            #pragma unroll
            for (int j = 0; j < 2; j++) {
                bf16x8 a = *(const bf16x8*)&T1[tadr((rtb + j) * 16 + lc, kk)];
                acc[j] = mfma16(a, b, acc[j]);
            }
        }
        #pragma unroll
        for (int j = 0; j < 2; j++)
            #pragma unroll
            for (int i = 0; i < 4; i++) {
                const int row = (rtb + j) * 16 + quad * 4 + i;
                out[(row0 + row) * 64 + nd] = acc[j][i] + bias;
            }
    }
}

extern "C" void kernel_launch(void* const* d_in, const int* in_sizes, int n_in,
                              void* d_out, int out_size, void* d_ws, size_t ws_size,
                              hipStream_t stream) {
    (void)in_sizes; (void)n_in; (void)out_size; (void)ws_size;
    const float* obs   = (const float*)d_in[0];
    const float* W_enc = (const float*)d_in[1];  const float* b_enc = (const float*)d_in[2];
    const float* W_obs = (const float*)d_in[3];  const float* b_obs = (const float*)d_in[4];
    const float* W_ih  = (const float*)d_in[5];  const float* b_ih  = (const float*)d_in[6];
    const float* W_hh  = (const float*)d_in[7];  const float* b_hh  = (const float*)d_in[8];
    const float* W_val = (const float*)d_in[9];  const float* b_val = (const float*)d_in[10];
    const float* W_dec = (const float*)d_in[11]; const float* b_dec = (const float*)d_in[12];
    float* out = (float*)d_out;
    __hip_bfloat16* ws = (__hip_bfloat16*)d_ws;

    prep_kernel<<<280, 256, 0, stream>>>(W_enc, W_obs, W_ih, W_hh, W_val, W_dec, ws);
    commnet_v6<<<256, 512, 0, stream>>>(
        ws, b_enc, b_obs, b_ih, b_hh, b_val, b_dec, obs, out);
}

// Round 13
// 146.981 us; speedup vs baseline: 1.0918x; 1.0502x over previous
//
#include <hip/hip_runtime.h>
#include <hip/hip_bf16.h>
#include <math.h>

// CommNetWork v7, MI355X gfx950. fp32 in / fp32 out.
// R12 lesson: register liveness > ~128 VGPR => spill (R7/R9/R12 all confirm).
// R10 (47us) is latency-bound at 1 block/CU (grid 256). v7: split every stage
// by OUTPUT COLUMNS (N) into 2 blocks/batch -> grid 512 = 2 blocks/CU, same
// per-CU weight traffic, same 4-row-tile A-density, column-local GRU epilogue.
// Stages become separate kernels (dispatch overhead measured flat ~75us).

typedef __bf16  bf16x8 __attribute__((ext_vector_type(8)));
typedef float   f32x4  __attribute__((ext_vector_type(4)));

#define DIN 128
#define H0  256
#define SW  264   // padded LDS stride for 256-wide staging
#define SWO 136   // padded LDS stride for obs staging
#define LOG2E 1.44269504088896f

// ws layout (bf16 elements)
#define O_WENC 0
#define O_WOBS 32768
#define O_WIH  98304
#define O_WHH  294912
#define O_WVAL 491520
#define O_WDEC 557056
#define W_TOT  573440
#define O_A    573440            // X1 then h' : 16384 x 256 bf16
#define O_B    4767744           // H  then V  : 16384 x 256 bf16
#define WS_NEED ((4767744 + 4194304) * 2)   // 17924096 bytes

__device__ __forceinline__ f32x4 mfma16(bf16x8 a, bf16x8 b, f32x4 c) {
    return __builtin_amdgcn_mfma_f32_16x16x32_bf16(a, b, c, 0, 0, 0);
}
__device__ __forceinline__ float bf2f(__hip_bfloat16 x) { return __bfloat162float(x); }
__device__ __forceinline__ __hip_bfloat16 f2bf(float x) { return __float2bfloat16(x); }
__device__ __forceinline__ float fsigmoid(float x) {
    float e = __builtin_amdgcn_exp2f(-LOG2E * x);
    return __builtin_amdgcn_rcpf(1.0f + e);
}
__device__ __forceinline__ float ftanh(float x) {
    float e = __builtin_amdgcn_exp2f(2.0f * LOG2E * x);
    return 1.0f - 2.0f * __builtin_amdgcn_rcpf(1.0f + e);
}
__device__ __forceinline__ bf16x8 w8(const __hip_bfloat16* p, int idx) {
    return *(const bf16x8*)(p + idx);
}

// stage a 64x256 bf16 row-major global tile into padded LDS (4 b128 per thread)
__device__ __forceinline__ void stage256(__hip_bfloat16* T, const __hip_bfloat16* g,
                                         int R0, int tid) {
    #pragma unroll
    for (int j = 0; j < 4; j++) {
        const int u = tid + j * 512;
        const int r = u >> 5, c = (u & 31) << 3;
        *(bf16x8*)&T[r * SW + c] = *(const bf16x8*)&g[(R0 + r) * 256 + c];
    }
}

// ---- prep: fp32 weights -> bf16 ws ----
__global__ __launch_bounds__(256) void prep_kernel(
    const float* __restrict__ W_enc, const float* __restrict__ W_obs,
    const float* __restrict__ W_ih,  const float* __restrict__ W_hh,
    const float* __restrict__ W_val, const float* __restrict__ W_dec,
    __hip_bfloat16* __restrict__ ws)
{
    const int i = (blockIdx.x * 256 + threadIdx.x) * 8;
    if (i >= W_TOT) return;
    const float* src; int off;
    if      (i < O_WOBS) { src = W_enc; off = O_WENC; }
    else if (i < O_WIH)  { src = W_obs; off = O_WOBS; }
    else if (i < O_WHH)  { src = W_ih;  off = O_WIH;  }
    else if (i < O_WVAL) { src = W_hh;  off = O_WHH;  }
    else if (i < O_WDEC) { src = W_val; off = O_WVAL; }
    else                 { src = W_dec; off = O_WDEC; }
    const float* f = src + (i - off);
    f32x4 a = *(const f32x4*)f;
    f32x4 b = *(const f32x4*)(f + 4);
    bf16x8 v;
    #pragma unroll
    for (int j = 0; j < 4; j++) { v[j] = (__bf16)a[j]; v[j + 4] = (__bf16)b[j]; }
    *(bf16x8*)(ws + i) = v;
}

// ---- K1a: X1 = relu(obs @ W_enc^T + b_enc), grid 512 (N-split) ----
__global__ __launch_bounds__(512, 2) void k_enc(
    const __hip_bfloat16* __restrict__ ws, const float* __restrict__ b_enc,
    const float* __restrict__ obs, __hip_bfloat16* __restrict__ X1g)
{
    __shared__ __align__(16) __hip_bfloat16 OB[64 * SWO];
    const __hip_bfloat16* W_enc = ws + O_WENC;

    const int tid = threadIdx.x, wave = tid >> 6, lane = tid & 63;
    const int quad = lane >> 4, lc = lane & 15, ko16 = quad * 8;
    const int R0 = (blockIdx.x >> 1) * 64;
    const int N0 = (blockIdx.x & 1) * 128;

    #pragma unroll
    for (int j = 0; j < 2; j++) {                 // stage obs fp32 -> bf16
        const int u = tid + j * 512;
        const int r = u >> 4, c = (u & 15) << 3;
        const float* src = obs + (R0 + r) * DIN + c;
        f32x4 a = *(const f32x4*)src;
        f32x4 b = *(const f32x4*)(src + 4);
        bf16x8 v;
        #pragma unroll
        for (int q = 0; q < 4; q++) { v[q] = (__bf16)a[q]; v[q + 4] = (__bf16)b[q]; }
        *(bf16x8*)&OB[r * SWO + c] = v;
    }
    __syncthreads();

    const int n = N0 + wave * 16 + lc;
    const float bias = b_enc[n];
    f32x4 acc[4] = {};
    #pragma unroll
    for (int k0 = 0; k0 < DIN; k0 += 32) {
        const int kk = k0 + ko16;
        bf16x8 b = w8(W_enc, n * DIN + kk);
        #pragma unroll
        for (int rt = 0; rt < 4; rt++) {
            bf16x8 a = *(const bf16x8*)&OB[(rt * 16 + lc) * SWO + kk];
            acc[rt] = mfma16(a, b, acc[rt]);
        }
    }
    #pragma unroll
    for (int rt = 0; rt < 4; rt++)
        #pragma unroll
        for (int i = 0; i < 4; i++) {
            const int row = rt * 16 + quad * 4 + i;
            X1g[(R0 + row) * 256 + n] = f2bf(fmaxf(acc[rt][i] + bias, 0.0f));
        }
}

// ---- K1b: H = X1 @ W_obs^T + b_obs, grid 512 (N-split) ----
__global__ __launch_bounds__(512, 2) void k_obs(
    const __hip_bfloat16* __restrict__ ws, const float* __restrict__ b_obs,
    const __hip_bfloat16* __restrict__ X1g, __hip_bfloat16* __restrict__ Hg)
{
    __shared__ __align__(16) __hip_bfloat16 T[64 * SW];
    const __hip_bfloat16* W_obs = ws + O_WOBS;

    const int tid = threadIdx.x, wave = tid >> 6, lane = tid & 63;
    const int quad = lane >> 4, lc = lane & 15, ko16 = quad * 8;
    const int R0 = (blockIdx.x >> 1) * 64;
    const int N0 = (blockIdx.x & 1) * 128;

    stage256(T, X1g, R0, tid);
    __syncthreads();

    const int n = N0 + wave * 16 + lc;
    const float bias = b_obs[n];
    f32x4 acc[4] = {};
    #pragma unroll 2
    for (int k0 = 0; k0 < H0; k0 += 32) {
        const int kk = k0 + ko16;
        bf16x8 b = w8(W_obs, n * H0 + kk);
        #pragma unroll
        for (int rt = 0; rt < 4; rt++) {
            bf16x8 a = *(const bf16x8*)&T[(rt * 16 + lc) * SW + kk];
            acc[rt] = mfma16(a, b, acc[rt]);
        }
    }
    #pragma unroll
    for (int rt = 0; rt < 4; rt++)
        #pragma unroll
        for (int i = 0; i < 4; i++) {
            const int row = rt * 16 + quad * 4 + i;
            Hg[(R0 + row) * 256 + n] = f2bf(acc[rt][i] + bias);
        }
}

// ---- K2: GRU with folded comm, grid 512 (N-split; colsum is column-local) ----
__global__ __launch_bounds__(512, 2) void k_gru(
    const __hip_bfloat16* __restrict__ ws,
    const float* __restrict__ b_ih, const float* __restrict__ b_hh,
    const __hip_bfloat16* __restrict__ Hg, __hip_bfloat16* __restrict__ HPg)
{
    __shared__ __align__(16) __hip_bfloat16 T[64 * SW];
    const __hip_bfloat16* W_ih = ws + O_WIH;
    const __hip_bfloat16* W_hh = ws + O_WHH;

    const int tid = threadIdx.x, wave = tid >> 6, lane = tid & 63;
    const int quad = lane >> 4, lc = lane & 15, ko16 = quad * 8;
    const int R0 = (blockIdx.x >> 1) * 64;
    const int N0 = (blockIdx.x & 1) * 128;

    stage256(T, Hg, R0, tid);
    __syncthreads();

    const int n = N0 + wave * 16 + lc;
    const float bir = b_ih[n], biz = b_ih[n + 256], bin = b_ih[n + 512];
    const float bhr = b_hh[n], bhz = b_hh[n + 256], bhn = b_hh[n + 512];
    f32x4 gir[4] = {}, giz[4] = {}, gin[4] = {};
    f32x4 ghr[4] = {}, ghz[4] = {}, ghn[4] = {};
    #pragma unroll 2
    for (int k0 = 0; k0 < H0; k0 += 32) {
        const int kk = k0 + ko16;
        bf16x8 bir8 = w8(W_ih, (n      ) * H0 + kk);
        bf16x8 biz8 = w8(W_ih, (n + 256) * H0 + kk);
        bf16x8 bin8 = w8(W_ih, (n + 512) * H0 + kk);
        bf16x8 bhr8 = w8(W_hh, (n      ) * H0 + kk);
        bf16x8 bhz8 = w8(W_hh, (n + 256) * H0 + kk);
        bf16x8 bhn8 = w8(W_hh, (n + 512) * H0 + kk);
        #pragma unroll
        for (int rt = 0; rt < 4; rt++) {
            bf16x8 aH = *(const bf16x8*)&T[(rt * 16 + lc) * SW + kk];
            gir[rt] = mfma16(aH, bir8, gir[rt]);
            giz[rt] = mfma16(aH, biz8, giz[rt]);
            gin[rt] = mfma16(aH, bin8, gin[rt]);
            ghr[rt] = mfma16(aH, bhr8, ghr[rt]);
            ghz[rt] = mfma16(aH, bhz8, ghz[rt]);
            ghn[rt] = mfma16(aH, bhn8, ghn[rt]);
        }
    }
    float Sr = 0.0f, Sz = 0.0f, Sn = 0.0f;
    #pragma unroll
    for (int rt = 0; rt < 4; rt++)
        #pragma unroll
        for (int i = 0; i < 4; i++) {
            Sr += gir[rt][i]; Sz += giz[rt][i]; Sn += gin[rt][i];
        }
    Sr += __shfl_xor(Sr, 16); Sr += __shfl_xor(Sr, 32);
    Sz += __shfl_xor(Sz, 16); Sz += __shfl_xor(Sz, 32);
    Sn += __shfl_xor(Sn, 16); Sn += __shfl_xor(Sn, 32);
    #pragma unroll
    for (int rt = 0; rt < 4; rt++)
        #pragma unroll
        for (int i = 0; i < 4; i++) {
            const int row = rt * 16 + quad * 4 + i;
            const float gi_r = (Sr - gir[rt][i]) * (1.0f / 64.0f) + bir;
            const float gi_z = (Sz - giz[rt][i]) * (1.0f / 64.0f) + biz;
            const float gi_n = (Sn - gin[rt][i]) * (1.0f / 64.0f) + bin;
            const float r  = fsigmoid(gi_r + ghr[rt][i] + bhr);
            const float z  = fsigmoid(gi_z + ghz[rt][i] + bhz);
            const float nn = ftanh(gi_n + r * (ghn[rt][i] + bhn));
            const float h  = bf2f(T[row * SW + n - N0 >= 0 ? row * SW + n : 0]); // placeholder (see below)
            (void)h;
            const float h2 = bf2f(T[row * SW + n]);   // T holds full 256-wide H rows
            HPg[(R0 + row) * 256 + n] = f2bf((1.0f - z) * nn + z * h2);
        }
}

// ---- K3a: V = h' @ W_val^T + b_val, grid 512 (N-split) ----
__global__ __launch_bounds__(512, 2) void k_val(
    const __hip_bfloat16* __restrict__ ws, const float* __restrict__ b_val,
    const __hip_bfloat16* __restrict__ HPg, __hip_bfloat16* __restrict__ Vg)
{
    __shared__ __align__(16) __hip_bfloat16 T[64 * SW];
    const __hip_bfloat16* W_val = ws + O_WVAL;

    const int tid = threadIdx.x, wave = tid >> 6, lane = tid & 63;
    const int quad = lane >> 4, lc = lane & 15, ko16 = quad * 8;
    const int R0 = (blockIdx.x >> 1) * 64;
    const int N0 = (blockIdx.x & 1) * 128;

    stage256(T, HPg, R0, tid);
    __syncthreads();

    const int n = N0 + wave * 16 + lc;
    const float bias = b_val[n];
    f32x4 acc[4] = {};
    #pragma unroll 2
    for (int k0 = 0; k0 < H0; k0 += 32) {
        const int kk = k0 + ko16;
        bf16x8 b = w8(W_val, n * H0 + kk);
        #pragma unroll
        for (int rt = 0; rt < 4; rt++) {
            bf16x8 a = *(const bf16x8*)&T[(rt * 16 + lc) * SW + kk];
            acc[rt] = mfma16(a, b, acc[rt]);
        }
    }
    #pragma unroll
    for (int rt = 0; rt < 4; rt++)
        #pragma unroll
        for (int i = 0; i < 4; i++) {
            const int row = rt * 16 + quad * 4 + i;
            Vg[(R0 + row) * 256 + n] = f2bf(acc[rt][i] + bias);
        }
}

// ---- K3b: OUT = V @ W_dec^T + b_dec, grid 256 ----
__global__ __launch_bounds__(512, 2) void k_dec(
    const __hip_bfloat16* __restrict__ ws, const float* __restrict__ b_dec,
    const __hip_bfloat16* __restrict__ Vg, float* __restrict__ out)
{
    __shared__ __align__(16) __hip_bfloat16 T[64 * SW];
    const __hip_bfloat16* W_dec = ws + O_WDEC;

    const int tid = threadIdx.x, wave = tid >> 6, lane = tid & 63;
    const int quad = lane >> 4, lc = lane & 15, ko16 = quad * 8;
    const int R0 = blockIdx.x * 64;

    stage256(T, Vg, R0, tid);
    __syncthreads();

    const int ct  = wave & 3;
    const int rtb = (wave >> 2) * 2;
    const int n   = ct * 16 + lc;
    const float bias = b_dec[n];
    f32x4 acc[2] = {};
    #pragma unroll 2
    for (int k0 = 0; k0 < H0; k0 += 32) {
        const int kk = k0 + ko16;
        bf16x8 b = w8(W_dec, n * H0 + kk);
        #pragma unroll
        for (int j = 0; j < 2; j++) {
            bf16x8 a = *(const bf16x8*)&T[((rtb + j) * 16 + lc) * SW + kk];
            acc[j] = mfma16(a, b, acc[j]);
        }
    }
    #pragma unroll
    for (int j = 0; j < 2; j++)
        #pragma unroll
        for (int i = 0; i < 4; i++) {
            const int row = (rtb + j) * 16 + quad * 4 + i;
            out[(R0 + row) * 64 + n] = acc[j][i] + bias;
        }
}

// ================= fallback: R10 fused kernel (proven 47us) =================
__global__ __launch_bounds__(512, 2) void commnet_fused(
    const __hip_bfloat16* __restrict__ ws,
    const float* __restrict__ b_enc, const float* __restrict__ b_obs,
    const float* __restrict__ b_ih,  const float* __restrict__ b_hh,
    const float* __restrict__ b_val, const float* __restrict__ b_dec,
    const float* __restrict__ obs,   float* __restrict__ out)
{
    __shared__ __align__(16) __hip_bfloat16 T0[64 * SW];
    __shared__ __align__(16) __hip_bfloat16 T1[64 * SW];
    const __hip_bfloat16* W_enc = ws + O_WENC;
    const __hip_bfloat16* W_obs = ws + O_WOBS;
    const __hip_bfloat16* W_ih  = ws + O_WIH;
    const __hip_bfloat16* W_hh  = ws + O_WHH;
    const __hip_bfloat16* W_val = ws + O_WVAL;
    const __hip_bfloat16* W_dec = ws + O_WDEC;

    const int tid = threadIdx.x, wave = tid >> 6, lane = tid & 63;
    const int quad = lane >> 4, lc = lane & 15, ko16 = quad * 8;
    const int row0 = blockIdx.x * 64;

    for (int i = tid; i < 64 * DIN / 8; i += 512) {
        const int r = i >> 4, c = (i & 15) << 3;
        const float* src = obs + (row0 + r) * DIN + c;
        f32x4 a = *(const f32x4*)src;
        f32x4 b = *(const f32x4*)(src + 4);
        bf16x8 v;
        #pragma unroll
        for (int j = 0; j < 4; j++) { v[j] = (__bf16)a[j]; v[j + 4] = (__bf16)b[j]; }
        *(bf16x8*)&T1[r * SWO + c] = v;
    }
    __syncthreads();

    #pragma unroll
    for (int cp = 0; cp < 2; cp++) {
        const int n = (wave + 8 * cp) * 16 + lc;
        const float bias = b_enc[n];
        f32x4 acc[4] = {};
        #pragma unroll
        for (int k0 = 0; k0 < DIN; k0 += 32) {
            const int kk = k0 + ko16;
            bf16x8 b = w8(W_enc, n * DIN + kk);
            #pragma unroll
            for (int rt = 0; rt < 4; rt++) {
                bf16x8 a = *(const bf16x8*)&T1[(rt * 16 + lc) * SWO + kk];
                acc[rt] = mfma16(a, b, acc[rt]);
            }
        }
        #pragma unroll
        for (int rt = 0; rt < 4; rt++)
            #pragma unroll
            for (int i = 0; i < 4; i++)
                T0[(rt * 16 + quad * 4 + i) * SW + n] = f2bf(fmaxf(acc[rt][i] + bias, 0.0f));
    }
    __syncthreads();

    #pragma unroll
    for (int cp = 0; cp < 2; cp++) {
        const int n = (wave + 8 * cp) * 16 + lc;
        const float bias = b_obs[n];
        f32x4 acc[4] = {};
        #pragma unroll 2
        for (int k0 = 0; k0 < H0; k0 += 32) {
            const int kk = k0 + ko16;
            bf16x8 b = w8(W_obs, n * H0 + kk);
            #pragma unroll
            for (int rt = 0; rt < 4; rt++) {
                bf16x8 a = *(const bf16x8*)&T0[(rt * 16 + lc) * SW + kk];
                acc[rt] = mfma16(a, b, acc[rt]);
            }
        }
        #pragma unroll
        for (int rt = 0; rt < 4; rt++)
            #pragma unroll
            for (int i = 0; i < 4; i++)
                T1[(rt * 16 + quad * 4 + i) * SW + n] = f2bf(acc[rt][i] + bias);
    }
    __syncthreads();

    #pragma unroll
    for (int cp = 0; cp < 2; cp++) {
        const int n = (wave + 8 * cp) * 16 + lc;
        const float bir = b_ih[n], biz = b_ih[n + 256], bin = b_ih[n + 512];
        const float bhr = b_hh[n], bhz = b_hh[n + 256], bhn = b_hh[n + 512];
        f32x4 gir[4] = {}, giz[4] = {}, gin[4] = {};
        f32x4 ghr[4] = {}, ghz[4] = {}, ghn[4] = {};
        #pragma unroll 2
        for (int k0 = 0; k0 < H0; k0 += 32) {
            const int kk = k0 + ko16;
            bf16x8 bir8 = w8(W_ih, (n      ) * H0 + kk);
            bf16x8 biz8 = w8(W_ih, (n + 256) * H0 + kk);
            bf16x8 bin8 = w8(W_ih, (n + 512) * H0 + kk);
            bf16x8 bhr8 = w8(W_hh, (n      ) * H0 + kk);
            bf16x8 bhz8 = w8(W_hh, (n + 256) * H0 + kk);
            bf16x8 bhn8 = w8(W_hh, (n + 512) * H0 + kk);
            #pragma unroll
            for (int rt = 0; rt < 4; rt++) {
                bf16x8 aH = *(const bf16x8*)&T1[(rt * 16 + lc) * SW + kk];
                gir[rt] = mfma16(aH, bir8, gir[rt]);
                giz[rt] = mfma16(aH, biz8, giz[rt]);
                gin[rt] = mfma16(aH, bin8, gin[rt]);
                ghr[rt] = mfma16(aH, bhr8, ghr[rt]);
                ghz[rt] = mfma16(aH, bhz8, ghz[rt]);
                ghn[rt] = mfma16(aH, bhn8, ghn[rt]);
            }
        }
        float Sr = 0.0f, Sz = 0.0f, Sn = 0.0f;
        #pragma unroll
        for (int rt = 0; rt < 4; rt++)
            #pragma unroll
            for (int i = 0; i < 4; i++) {
                Sr += gir[rt][i]; Sz += giz[rt][i]; Sn += gin[rt][i];
            }
        Sr += __shfl_xor(Sr, 16); Sr += __shfl_xor(Sr, 32);
        Sz += __shfl_xor(Sz, 16); Sz += __shfl_xor(Sz, 32);
        Sn += __shfl_xor(Sn, 16); Sn += __shfl_xor(Sn, 32);
        #pragma unroll
        for (int rt = 0; rt < 4; rt++)
            #pragma unroll
            for (int i = 0; i < 4; i++) {
                const int row = rt * 16 + quad * 4 + i;
                const float gi_r = (Sr - gir[rt][i]) * (1.0f / 64.0f) + bir;
                const float gi_z = (Sz - giz[rt][i]) * (1.0f / 64.0f) + biz;
                const float gi_n = (Sn - gin[rt][i]) * (1.0f / 64.0f) + bin;
                const float r  = fsigmoid(gi_r + ghr[rt][i] + bhr);
                const float z  = fsigmoid(gi_z + ghz[rt][i] + bhz);
                const float nn = ftanh(gi_n + r * (ghn[rt][i] + bhn));
                const float h  = bf2f(T1[row * SW + n]);
                T0[row * SW + n] = f2bf((1.0f - z) * nn + z * h);
            }
    }
    __syncthreads();

    #pragma unroll
    for (int cp = 0; cp < 2; cp++) {
        const int n = (wave + 8 * cp) * 16 + lc;
        const float bias = b_val[n];
        f32x4 acc[4] = {};
        #pragma unroll 2
        for (int k0 = 0; k0 < H0; k0 += 32) {
            const int kk = k0 + ko16;
            bf16x8 b = w8(W_val, n * H0 + kk);
            #pragma unroll
            for (int rt = 0; rt < 4; rt++) {
                bf16x8 a = *(const bf16x8*)&T0[(rt * 16 + lc) * SW + kk];
                acc[rt] = mfma16(a, b, acc[rt]);
            }
        }
        #pragma unroll
        for (int rt = 0; rt < 4; rt++)
            #pragma unroll
            for (int i = 0; i < 4; i++)
                T1[(rt * 16 + quad * 4 + i) * SW + n] = f2bf(acc[rt][i] + bias);
    }
    __syncthreads();

    {
        const int ct  = wave & 3;
        const int rtb = (wave >> 2) * 2;
        const int n   = ct * 16 + lc;
        const float bias = b_dec[n];
        f32x4 acc[2] = {};
        #pragma unroll 2
        for (int k0 = 0; k0 < H0; k0 += 32) {
            const int kk = k0 + ko16;
            bf16x8 b = w8(W_dec, n * H0 + kk);
            #pragma unroll
            for (int j = 0; j < 2; j++) {
                bf16x8 a = *(const bf16x8*)&T1[((rtb + j) * 16 + lc) * SW + kk];
                acc[j] = mfma16(a, b, acc[j]);
            }
        }
        #pragma unroll
        for (int j = 0; j < 2; j++)
            #pragma unroll
            for (int i = 0; i < 4; i++) {
                const int row = (rtb + j) * 16 + quad * 4 + i;
                out[(row0 + row) * 64 + n] = acc[j][i] + bias;
            }
    }
}

extern "C" void kernel_launch(void* const* d_in, const int* in_sizes, int n_in,
                              void* d_out, int out_size, void* d_ws, size_t ws_size,
                              hipStream_t stream) {
    (void)in_sizes; (void)n_in; (void)out_size;
    const float* obs   = (const float*)d_in[0];
    const float* W_enc = (const float*)d_in[1];  const float* b_enc = (const float*)d_in[2];
    const float* W_obs = (const float*)d_in[3];  const float* b_obs = (const float*)d_in[4];
    const float* W_ih  = (const float*)d_in[5];  const float* b_ih  = (const float*)d_in[6];
    const float* W_hh  = (const float*)d_in[7];  const float* b_hh  = (const float*)d_in[8];
    const float* W_val = (const float*)d_in[9];  const float* b_val = (const float*)d_in[10];
    const float* W_dec = (const float*)d_in[11]; const float* b_dec = (const float*)d_in[12];
    float* out = (float*)d_out;
    __hip_bfloat16* ws = (__hip_bfloat16*)d_ws;

    prep_kernel<<<280, 256, 0, stream>>>(W_enc, W_obs, W_ih, W_hh, W_val, W_dec, ws);

    if (ws_size >= (size_t)WS_NEED) {
        __hip_bfloat16* A = ws + O_A;   // X1, then h'
        __hip_bfloat16* B = ws + O_B;   // H, then V
        k_enc<<<512, 512, 0, stream>>>(ws, b_enc, obs, A);
        k_obs<<<512, 512, 0, stream>>>(ws, b_obs, A, B);
        k_gru<<<512, 512, 0, stream>>>(ws, b_ih, b_hh, B, A);
        k_val<<<512, 512, 0, stream>>>(ws, b_val, A, B);
        k_dec<<<256, 512, 0, stream>>>(ws, b_dec, B, out);
    } else {
        commnet_fused<<<256, 512, 0, stream>>>(
            ws, b_enc, b_obs, b_ih, b_hh, b_val, b_dec, obs, out);
    }
}

// Round 14
// 134.736 us; speedup vs baseline: 1.1910x; 1.0909x over previous
//
#include <hip/hip_runtime.h>
#include <hip/hip_bf16.h>
#include <math.h>

// CommNetWork v8, MI355X gfx950. fp32 in / fp32 out.
// R13 findings: the ~75us total-vs-dispatch gap is the harness re-poisoning
// the 256MB d_ws (42us fill) + input restores -- fixed floor, untouchable.
// Multi-kernel staging loses (each stage pays a global round-trip); R10's
// fused 47us kernel is the platform. v8 shrinks it:
//  1) val+dec folded: out = h'@(W_dec.W_val)^T + (W_dec.b_val + b_dec);
//     W_vd/b_vd precomputed in a tiny kernel -> one whole GEMM stage gone.
//  2) __launch_bounds__(512,1): grid is 256 (1 block/CU) so no occupancy
//     loss, but lifts the empirical 128-VGPR cap that (512,2) imposes
//     (R7/R8/R12 spills). Enables depth-1 weight prefetch in all K-loops
//     (wrap-indexed, branchless) to hide L2 latency behind MFMAs.

typedef __bf16  bf16x8 __attribute__((ext_vector_type(8)));
typedef float   f32x4  __attribute__((ext_vector_type(4)));

#define DIN 128
#define H0  256
#define SW  264   // padded LDS stride (256-wide tiles)
#define SWO 136   // padded LDS stride (obs tile)
#define LOG2E 1.44269504088896f

// ws layout (bf16 elements)
#define O_WENC 0
#define O_WOBS 32768
#define O_WIH  98304
#define O_WHH  294912
#define W_TOT4 491520            // prep converts 4 matrices
#define O_WVD  491520            // W_vd = W_dec @ W_val : 64 x 256 bf16
#define BVD_BYTE 1015808         // fp32 b_vd[64] at byte offset (16-aligned)

__device__ __forceinline__ f32x4 mfma16(bf16x8 a, bf16x8 b, f32x4 c) {
    return __builtin_amdgcn_mfma_f32_16x16x32_bf16(a, b, c, 0, 0, 0);
}
__device__ __forceinline__ float bf2f(__hip_bfloat16 x) { return __bfloat162float(x); }
__device__ __forceinline__ __hip_bfloat16 f2bf(float x) { return __float2bfloat16(x); }
__device__ __forceinline__ float fsigmoid(float x) {
    float e = __builtin_amdgcn_exp2f(-LOG2E * x);
    return __builtin_amdgcn_rcpf(1.0f + e);
}
__device__ __forceinline__ float ftanh(float x) {
    float e = __builtin_amdgcn_exp2f(2.0f * LOG2E * x);
    return 1.0f - 2.0f * __builtin_amdgcn_rcpf(1.0f + e);
}
__device__ __forceinline__ bf16x8 w8(const __hip_bfloat16* p, int idx) {
    return *(const bf16x8*)(p + idx);
}

// ---- prep: convert W_enc/W_obs/W_ih/W_hh fp32 -> bf16 ws (240 blocks) ----
__global__ __launch_bounds__(256) void prep_kernel(
    const float* __restrict__ W_enc, const float* __restrict__ W_obs,
    const float* __restrict__ W_ih,  const float* __restrict__ W_hh,
    __hip_bfloat16* __restrict__ ws)
{
    const int i = (blockIdx.x * 256 + threadIdx.x) * 8;
    if (i >= W_TOT4) return;
    const float* src; int off;
    if      (i < O_WOBS) { src = W_enc; off = O_WENC; }
    else if (i < O_WIH)  { src = W_obs; off = O_WOBS; }
    else if (i < O_WHH)  { src = W_ih;  off = O_WIH;  }
    else                 { src = W_hh;  off = O_WHH;  }
    const float* f = src + (i - off);
    f32x4 a = *(const f32x4*)f;
    f32x4 b = *(const f32x4*)(f + 4);
    bf16x8 v;
    #pragma unroll
    for (int j = 0; j < 4; j++) { v[j] = (__bf16)a[j]; v[j + 4] = (__bf16)b[j]; }
    *(bf16x8*)(ws + i) = v;
}

// ---- W_vd = W_dec @ W_val (fp32 accum), b_vd = W_dec@b_val + b_dec ----
// grid 64 (one block per output row o), 256 threads (one per col h).
__global__ __launch_bounds__(256) void wvd_kernel(
    const float* __restrict__ W_dec, const float* __restrict__ W_val,
    const float* __restrict__ b_val, const float* __restrict__ b_dec,
    __hip_bfloat16* __restrict__ wvd, float* __restrict__ bvd)
{
    const int o = blockIdx.x;
    const int h = threadIdx.x;
    float acc = 0.0f;
    for (int v = 0; v < 256; v++)
        acc += W_dec[o * 256 + v] * W_val[v * 256 + h];   // W_dec bcast, W_val coalesced
    wvd[o * 256 + h] = f2bf(acc);
    if (h == 0) {
        float b = b_dec[o];
        for (int v = 0; v < 256; v++) b += W_dec[o * 256 + v] * b_val[v];
        bvd[o] = b;
    }
}

__global__ __launch_bounds__(512, 1) void commnet_v8(
    const __hip_bfloat16* __restrict__ ws, const float* __restrict__ bvd,
    const float* __restrict__ b_enc, const float* __restrict__ b_obs,
    const float* __restrict__ b_ih,  const float* __restrict__ b_hh,
    const float* __restrict__ obs,   float* __restrict__ out)
{
    __shared__ __align__(16) __hip_bfloat16 T0[64 * SW];  // X1 -> h'
    __shared__ __align__(16) __hip_bfloat16 T1[64 * SW];  // obs -> H

    const __hip_bfloat16* W_enc = ws + O_WENC;
    const __hip_bfloat16* W_obs = ws + O_WOBS;
    const __hip_bfloat16* W_ih  = ws + O_WIH;
    const __hip_bfloat16* W_hh  = ws + O_WHH;
    const __hip_bfloat16* W_vd  = ws + O_WVD;

    const int tid  = threadIdx.x;
    const int wave = tid >> 6;
    const int lane = tid & 63;
    const int quad = lane >> 4;
    const int lc   = lane & 15;
    const int row0 = blockIdx.x * 64;
    const int ko16 = quad * 8;

    // ---- stage obs (fp32 global) -> bf16 padded T1 ----
    #pragma unroll
    for (int j = 0; j < 2; j++) {
        const int u = tid + j * 512;
        const int r = u >> 4, c = (u & 15) << 3;
        const float* src = obs + (row0 + r) * DIN + c;
        f32x4 a = *(const f32x4*)src;
        f32x4 b = *(const f32x4*)(src + 4);
        bf16x8 v;
        #pragma unroll
        for (int q = 0; q < 4; q++) { v[q] = (__bf16)a[q]; v[q + 4] = (__bf16)b[q]; }
        *(bf16x8*)&T1[r * SWO + c] = v;
    }
    __syncthreads();

    // ---- ENC: X1 = relu(obs @ W_enc^T + b_enc) -> T0 ----
    #pragma unroll
    for (int cp = 0; cp < 2; cp++) {
        const int n = (wave + 8 * cp) * 16 + lc;
        const float bias = b_enc[n];
        f32x4 acc[4] = {};
        bf16x8 wc = w8(W_enc, n * DIN + ko16);
        #pragma unroll
        for (int k0 = 0; k0 < DIN; k0 += 32) {
            bf16x8 wn = w8(W_enc, n * DIN + (((k0 + 32) & (DIN - 1)) + ko16));
            const int kk = k0 + ko16;
            #pragma unroll
            for (int rt = 0; rt < 4; rt++) {
                bf16x8 a = *(const bf16x8*)&T1[(rt * 16 + lc) * SWO + kk];
                acc[rt] = mfma16(a, wc, acc[rt]);
            }
            wc = wn;
        }
        #pragma unroll
        for (int rt = 0; rt < 4; rt++)
            #pragma unroll
            for (int i = 0; i < 4; i++)
                T0[(rt * 16 + quad * 4 + i) * SW + n] = f2bf(fmaxf(acc[rt][i] + bias, 0.0f));
    }
    __syncthreads();

    // ---- OBS: H = X1 @ W_obs^T + b_obs -> T1 ----
    #pragma unroll
    for (int cp = 0; cp < 2; cp++) {
        const int n = (wave + 8 * cp) * 16 + lc;
        const float bias = b_obs[n];
        f32x4 acc[4] = {};
        bf16x8 wc = w8(W_obs, n * H0 + ko16);
        #pragma unroll 2
        for (int k0 = 0; k0 < H0; k0 += 32) {
            bf16x8 wn = w8(W_obs, n * H0 + (((k0 + 32) & (H0 - 1)) + ko16));
            const int kk = k0 + ko16;
            #pragma unroll
            for (int rt = 0; rt < 4; rt++) {
                bf16x8 a = *(const bf16x8*)&T0[(rt * 16 + lc) * SW + kk];
                acc[rt] = mfma16(a, wc, acc[rt]);
            }
            wc = wn;
        }
        #pragma unroll
        for (int rt = 0; rt < 4; rt++)
            #pragma unroll
            for (int i = 0; i < 4; i++)
                T1[(rt * 16 + quad * 4 + i) * SW + n] = f2bf(acc[rt][i] + bias);
    }
    __syncthreads();

    // ---- GRU with folded comm: gi = (colsum(G) - G)/64 + b_ih, G = H@W_ih^T ----
    #pragma unroll
    for (int cp = 0; cp < 2; cp++) {
        const int n = (wave + 8 * cp) * 16 + lc;
        const float bir = b_ih[n], biz = b_ih[n + 256], bin = b_ih[n + 512];
        const float bhr = b_hh[n], bhz = b_hh[n + 256], bhn = b_hh[n + 512];
        f32x4 gir[4] = {}, giz[4] = {}, gin[4] = {};
        f32x4 ghr[4] = {}, ghz[4] = {}, ghn[4] = {};
        bf16x8 c0 = w8(W_ih, (n      ) * H0 + ko16);
        bf16x8 c1 = w8(W_ih, (n + 256) * H0 + ko16);
        bf16x8 c2 = w8(W_ih, (n + 512) * H0 + ko16);
        bf16x8 c3 = w8(W_hh, (n      ) * H0 + ko16);
        bf16x8 c4 = w8(W_hh, (n + 256) * H0 + ko16);
        bf16x8 c5 = w8(W_hh, (n + 512) * H0 + ko16);
        #pragma unroll 2
        for (int k0 = 0; k0 < H0; k0 += 32) {
            const int kn = ((k0 + 32) & (H0 - 1)) + ko16;
            bf16x8 d0 = w8(W_ih, (n      ) * H0 + kn);
            bf16x8 d1 = w8(W_ih, (n + 256) * H0 + kn);
            bf16x8 d2 = w8(W_ih, (n + 512) * H0 + kn);
            bf16x8 d3 = w8(W_hh, (n      ) * H0 + kn);
            bf16x8 d4 = w8(W_hh, (n + 256) * H0 + kn);
            bf16x8 d5 = w8(W_hh, (n + 512) * H0 + kn);
            const int kk = k0 + ko16;
            #pragma unroll
            for (int rt = 0; rt < 4; rt++) {
                bf16x8 aH = *(const bf16x8*)&T1[(rt * 16 + lc) * SW + kk];
                gir[rt] = mfma16(aH, c0, gir[rt]);
                giz[rt] = mfma16(aH, c1, giz[rt]);
                gin[rt] = mfma16(aH, c2, gin[rt]);
                ghr[rt] = mfma16(aH, c3, ghr[rt]);
                ghz[rt] = mfma16(aH, c4, ghz[rt]);
                ghn[rt] = mfma16(aH, c5, ghn[rt]);
            }
            c0 = d0; c1 = d1; c2 = d2; c3 = d3; c4 = d4; c5 = d5;
        }
        float Sr = 0.0f, Sz = 0.0f, Sn = 0.0f;
        #pragma unroll
        for (int rt = 0; rt < 4; rt++)
            #pragma unroll
            for (int i = 0; i < 4; i++) {
                Sr += gir[rt][i]; Sz += giz[rt][i]; Sn += gin[rt][i];
            }
        Sr += __shfl_xor(Sr, 16); Sr += __shfl_xor(Sr, 32);
        Sz += __shfl_xor(Sz, 16); Sz += __shfl_xor(Sz, 32);
        Sn += __shfl_xor(Sn, 16); Sn += __shfl_xor(Sn, 32);
        #pragma unroll
        for (int rt = 0; rt < 4; rt++)
            #pragma unroll
            for (int i = 0; i < 4; i++) {
                const int row = rt * 16 + quad * 4 + i;
                const float gi_r = (Sr - gir[rt][i]) * (1.0f / 64.0f) + bir;
                const float gi_z = (Sz - giz[rt][i]) * (1.0f / 64.0f) + biz;
                const float gi_n = (Sn - gin[rt][i]) * (1.0f / 64.0f) + bin;
                const float r  = fsigmoid(gi_r + ghr[rt][i] + bhr);
                const float z  = fsigmoid(gi_z + ghz[rt][i] + bhz);
                const float nn = ftanh(gi_n + r * (ghn[rt][i] + bhn));
                const float h  = bf2f(T1[row * SW + n]);
                T0[row * SW + n] = f2bf((1.0f - z) * nn + z * h);
            }
    }
    __syncthreads();

    // ---- OUT: out = h' @ W_vd^T + b_vd  (val+dec folded) ----
    {
        const int ct  = wave & 3;          // 4 col-tiles (H2=64)
        const int rtb = (wave >> 2) * 2;   // waves 0-3: rows 0..31, 4-7: 32..63
        const int n   = ct * 16 + lc;
        const float bias = bvd[n];
        f32x4 acc[2] = {};
        bf16x8 wc = w8(W_vd, n * H0 + ko16);
        #pragma unroll
        for (int k0 = 0; k0 < H0; k0 += 32) {
            bf16x8 wn = w8(W_vd, n * H0 + (((k0 + 32) & (H0 - 1)) + ko16));
            const int kk = k0 + ko16;
            #pragma unroll
            for (int j = 0; j < 2; j++) {
                bf16x8 a = *(const bf16x8*)&T0[((rtb + j) * 16 + lc) * SW + kk];
                acc[j] = mfma16(a, wc, acc[j]);
            }
            wc = wn;
        }
        #pragma unroll
        for (int j = 0; j < 2; j++)
            #pragma unroll
            for (int i = 0; i < 4; i++) {
                const int row = (rtb + j) * 16 + quad * 4 + i;
                out[(row0 + row) * 64 + n] = acc[j][i] + bias;
            }
    }
}

extern "C" void kernel_launch(void* const* d_in, const int* in_sizes, int n_in,
                              void* d_out, int out_size, void* d_ws, size_t ws_size,
                              hipStream_t stream) {
    (void)in_sizes; (void)n_in; (void)out_size; (void)ws_size;
    const float* obs   = (const float*)d_in[0];
    const float* W_enc = (const float*)d_in[1];  const float* b_enc = (const float*)d_in[2];
    const float* W_obs = (const float*)d_in[3];  const float* b_obs = (const float*)d_in[4];
    const float* W_ih  = (const float*)d_in[5];  const float* b_ih  = (const float*)d_in[6];
    const float* W_hh  = (const float*)d_in[7];  const float* b_hh  = (const float*)d_in[8];
    const float* W_val = (const float*)d_in[9];  const float* b_val = (const float*)d_in[10];
    const float* W_dec = (const float*)d_in[11]; const float* b_dec = (const float*)d_in[12];
    float* out = (float*)d_out;
    __hip_bfloat16* ws = (__hip_bfloat16*)d_ws;
    float* bvd = (float*)((char*)d_ws + BVD_BYTE);

    prep_kernel<<<240, 256, 0, stream>>>(W_enc, W_obs, W_ih, W_hh, ws);
    wvd_kernel<<<64, 256, 0, stream>>>(W_dec, W_val, b_val, b_dec, ws + O_WVD, bvd);
    commnet_v8<<<256, 512, 0, stream>>>(ws, bvd, b_enc, b_obs, b_ih, b_hh, obs, out);
}

// Round 15
// 127.843 us; speedup vs baseline: 1.2552x; 1.0539x over previous
//
#include <hip/hip_runtime.h>
#include <hip/hip_bf16.h>
#include <math.h>

// CommNetWork v9, MI355X gfx950. fp32 in / fp32 out.
// R14: main kernel latency-bound at 2 waves/SIMD (32% combined pipe util);
// separate wvd dispatch cost +15us serialized. v9:
//  1) 1024-thr main (16 waves = 4/SIMD), occupancy pinned via
//     amdgpu_waves_per_eu(4,4) (R9's failure was the compiler heuristic
//     targeting 8 waves/EU -> 64 VGPR -> spill). GRU split into two passes
//     (r/z: 16 accs, r parked bf16 in dead T0, z in regs; n: 8 accs) to fit
//     the 128-reg/wave budget.
//  2) wvd folded into the prep dispatch (grid 304) -- no third launch.

typedef __bf16  bf16x8 __attribute__((ext_vector_type(8)));
typedef float   f32x4  __attribute__((ext_vector_type(4)));

#define DIN 128
#define H0  256
#define SW  264   // padded LDS stride (256-wide tiles)
#define SWO 136   // padded LDS stride (obs tile)
#define LOG2E 1.44269504088896f

// ws layout (bf16 elements)
#define O_WENC 0
#define O_WOBS 32768
#define O_WIH  98304
#define O_WHH  294912
#define W_TOT4 491520            // 4 converted matrices (240 blocks x 2048 elems)
#define O_WVD  491520            // W_vd = W_dec @ W_val : 64 x 256 bf16
#define BVD_BYTE 1015808         // fp32 b_vd[64] (16-aligned byte offset)

__device__ __forceinline__ f32x4 mfma16(bf16x8 a, bf16x8 b, f32x4 c) {
    return __builtin_amdgcn_mfma_f32_16x16x32_bf16(a, b, c, 0, 0, 0);
}
__device__ __forceinline__ float bf2f(__hip_bfloat16 x) { return __bfloat162float(x); }
__device__ __forceinline__ __hip_bfloat16 f2bf(float x) { return __float2bfloat16(x); }
__device__ __forceinline__ float fsigmoid(float x) {
    float e = __builtin_amdgcn_exp2f(-LOG2E * x);
    return __builtin_amdgcn_rcpf(1.0f + e);
}
__device__ __forceinline__ float ftanh(float x) {
    float e = __builtin_amdgcn_exp2f(2.0f * LOG2E * x);
    return 1.0f - 2.0f * __builtin_amdgcn_rcpf(1.0f + e);
}
__device__ __forceinline__ bf16x8 w8(const __hip_bfloat16* p, int idx) {
    return *(const bf16x8*)(p + idx);
}

// ---- prep (blocks 0..239): fp32 W_enc/W_obs/W_ih/W_hh -> bf16 ws
//      (blocks 240..303): W_vd = W_dec@W_val (fp32 accum, 4-way ILP), b_vd ----
__global__ __launch_bounds__(256) void prep_kernel(
    const float* __restrict__ W_enc, const float* __restrict__ W_obs,
    const float* __restrict__ W_ih,  const float* __restrict__ W_hh,
    const float* __restrict__ W_val, const float* __restrict__ W_dec,
    const float* __restrict__ b_val, const float* __restrict__ b_dec,
    __hip_bfloat16* __restrict__ ws, float* __restrict__ bvd)
{
    if (blockIdx.x < 240) {
        const int i = (blockIdx.x * 256 + threadIdx.x) * 8;
        const float* src; int off;
        if      (i < O_WOBS) { src = W_enc; off = O_WENC; }
        else if (i < O_WIH)  { src = W_obs; off = O_WOBS; }
        else if (i < O_WHH)  { src = W_ih;  off = O_WIH;  }
        else                 { src = W_hh;  off = O_WHH;  }
        const float* f = src + (i - off);
        f32x4 a = *(const f32x4*)f;
        f32x4 b = *(const f32x4*)(f + 4);
        bf16x8 v;
        #pragma unroll
        for (int j = 0; j < 4; j++) { v[j] = (__bf16)a[j]; v[j + 4] = (__bf16)b[j]; }
        *(bf16x8*)(ws + i) = v;
    } else {
        const int o = blockIdx.x - 240;    // 0..63
        const int h = threadIdx.x;         // 0..255
        const float* wd = W_dec + o * 256;
        float a0 = 0.f, a1 = 0.f, a2 = 0.f, a3 = 0.f;
        for (int v4 = 0; v4 < 64; v4++) {
            const int v = v4 * 4;
            a0 += wd[v    ] * W_val[(v    ) * 256 + h];
            a1 += wd[v + 1] * W_val[(v + 1) * 256 + h];
            a2 += wd[v + 2] * W_val[(v + 2) * 256 + h];
            a3 += wd[v + 3] * W_val[(v + 3) * 256 + h];
        }
        ws[O_WVD + o * 256 + h] = f2bf((a0 + a1) + (a2 + a3));
        if (h == 0) {
            float b0 = 0.f, b1 = 0.f, b2 = 0.f, b3 = 0.f;
            for (int v4 = 0; v4 < 64; v4++) {
                const int v = v4 * 4;
                b0 += wd[v] * b_val[v];     b1 += wd[v + 1] * b_val[v + 1];
                b2 += wd[v + 2] * b_val[v + 2]; b3 += wd[v + 3] * b_val[v + 3];
            }
            bvd[o] = b_dec[o] + (b0 + b1) + (b2 + b3);
        }
    }
}

__global__ __attribute__((amdgpu_flat_work_group_size(1024, 1024),
                          amdgpu_waves_per_eu(4, 4)))
void commnet_v9(
    const __hip_bfloat16* __restrict__ ws, const float* __restrict__ bvd,
    const float* __restrict__ b_enc, const float* __restrict__ b_obs,
    const float* __restrict__ b_ih,  const float* __restrict__ b_hh,
    const float* __restrict__ obs,   float* __restrict__ out)
{
    __shared__ __align__(16) __hip_bfloat16 T0[64 * SW];  // X1 -> r -> h'
    __shared__ __align__(16) __hip_bfloat16 T1[64 * SW];  // obs -> H

    const __hip_bfloat16* W_enc = ws + O_WENC;
    const __hip_bfloat16* W_obs = ws + O_WOBS;
    const __hip_bfloat16* W_ih  = ws + O_WIH;
    const __hip_bfloat16* W_hh  = ws + O_WHH;
    const __hip_bfloat16* W_vd  = ws + O_WVD;

    const int tid  = threadIdx.x;
    const int wave = tid >> 6;           // 0..15
    const int lane = tid & 63;
    const int quad = lane >> 4;
    const int lc   = lane & 15;
    const int row0 = blockIdx.x * 64;
    const int ko16 = quad * 8;
    const int n    = wave * 16 + lc;     // this wave's column (256-wide stages)

    // ---- stage obs (fp32 global) -> bf16 padded T1: exactly 1 chunk/thread ----
    {
        const int r = tid >> 4, c = (tid & 15) << 3;
        const float* src = obs + (row0 + r) * DIN + c;
        f32x4 a = *(const f32x4*)src;
        f32x4 b = *(const f32x4*)(src + 4);
        bf16x8 v;
        #pragma unroll
        for (int q = 0; q < 4; q++) { v[q] = (__bf16)a[q]; v[q + 4] = (__bf16)b[q]; }
        *(bf16x8*)&T1[r * SWO + c] = v;
    }
    __syncthreads();

    // ---- ENC: X1 = relu(obs @ W_enc^T + b_enc) -> T0 ----
    {
        const float bias = b_enc[n];
        f32x4 acc[4] = {};
        bf16x8 wc = w8(W_enc, n * DIN + ko16);
        #pragma unroll
        for (int k0 = 0; k0 < DIN; k0 += 32) {
            bf16x8 wn = w8(W_enc, n * DIN + (((k0 + 32) & (DIN - 1)) + ko16));
            const int kk = k0 + ko16;
            #pragma unroll
            for (int rt = 0; rt < 4; rt++) {
                bf16x8 a = *(const bf16x8*)&T1[(rt * 16 + lc) * SWO + kk];
                acc[rt] = mfma16(a, wc, acc[rt]);
            }
            wc = wn;
        }
        #pragma unroll
        for (int rt = 0; rt < 4; rt++)
            #pragma unroll
            for (int i = 0; i < 4; i++)
                T0[(rt * 16 + quad * 4 + i) * SW + n] = f2bf(fmaxf(acc[rt][i] + bias, 0.0f));
    }
    __syncthreads();

    // ---- OBS: H = X1 @ W_obs^T + b_obs -> T1 ----
    {
        const float bias = b_obs[n];
        f32x4 acc[4] = {};
        bf16x8 wc = w8(W_obs, n * H0 + ko16);
        #pragma unroll 2
        for (int k0 = 0; k0 < H0; k0 += 32) {
            bf16x8 wn = w8(W_obs, n * H0 + (((k0 + 32) & (H0 - 1)) + ko16));
            const int kk = k0 + ko16;
            #pragma unroll
            for (int rt = 0; rt < 4; rt++) {
                bf16x8 a = *(const bf16x8*)&T0[(rt * 16 + lc) * SW + kk];
                acc[rt] = mfma16(a, wc, acc[rt]);
            }
            wc = wn;
        }
        #pragma unroll
        for (int rt = 0; rt < 4; rt++)
            #pragma unroll
            for (int i = 0; i < 4; i++)
                T1[(rt * 16 + quad * 4 + i) * SW + n] = f2bf(acc[rt][i] + bias);
    }
    __syncthreads();

    // ---- GRU with folded comm, two passes to fit 128 regs/wave ----
    // gi = (colsum(G) - G)/64 + b_ih, G = H@W_ih^T (colsum commutes with @W^T).
    // Pass A: r,z gates (16 accs). r -> T0 bf16 (X1 dead, own-lane slots), z -> regs.
    f32x4 zreg[4];
    {
        const float bir = b_ih[n], biz = b_ih[n + 256];
        const float bhr = b_hh[n], bhz = b_hh[n + 256];
        f32x4 gir[4] = {}, giz[4] = {}, ghr[4] = {}, ghz[4] = {};
        #pragma unroll 2
        for (int k0 = 0; k0 < H0; k0 += 32) {
            const int kk = k0 + ko16;
            bf16x8 c0 = w8(W_ih, (n      ) * H0 + kk);
            bf16x8 c1 = w8(W_ih, (n + 256) * H0 + kk);
            bf16x8 c3 = w8(W_hh, (n      ) * H0 + kk);
            bf16x8 c4 = w8(W_hh, (n + 256) * H0 + kk);
            #pragma unroll
            for (int rt = 0; rt < 4; rt++) {
                bf16x8 aH = *(const bf16x8*)&T1[(rt * 16 + lc) * SW + kk];
                gir[rt] = mfma16(aH, c0, gir[rt]);
                giz[rt] = mfma16(aH, c1, giz[rt]);
                ghr[rt] = mfma16(aH, c3, ghr[rt]);
                ghz[rt] = mfma16(aH, c4, ghz[rt]);
            }
        }
        float Sr = 0.0f, Sz = 0.0f;
        #pragma unroll
        for (int rt = 0; rt < 4; rt++)
            #pragma unroll
            for (int i = 0; i < 4; i++) { Sr += gir[rt][i]; Sz += giz[rt][i]; }
        Sr += __shfl_xor(Sr, 16); Sr += __shfl_xor(Sr, 32);
        Sz += __shfl_xor(Sz, 16); Sz += __shfl_xor(Sz, 32);
        #pragma unroll
        for (int rt = 0; rt < 4; rt++)
            #pragma unroll
            for (int i = 0; i < 4; i++) {
                const int row = rt * 16 + quad * 4 + i;
                const float gi_r = (Sr - gir[rt][i]) * (1.0f / 64.0f) + bir;
                const float gi_z = (Sz - giz[rt][i]) * (1.0f / 64.0f) + biz;
                T0[row * SW + n] = f2bf(fsigmoid(gi_r + ghr[rt][i] + bhr));
                zreg[rt][i]      = fsigmoid(gi_z + ghz[rt][i] + bhz);
            }
    }
    // Pass B: n gate + h' (8 accs). Reads own r slots from T0; h' -> T0.
    {
        const float bin = b_ih[n + 512], bhn = b_hh[n + 512];
        f32x4 gin[4] = {}, ghn[4] = {};
        #pragma unroll 2
        for (int k0 = 0; k0 < H0; k0 += 32) {
            const int kk = k0 + ko16;
            bf16x8 c2 = w8(W_ih, (n + 512) * H0 + kk);
            bf16x8 c5 = w8(W_hh, (n + 512) * H0 + kk);
            #pragma unroll
            for (int rt = 0; rt < 4; rt++) {
                bf16x8 aH = *(const bf16x8*)&T1[(rt * 16 + lc) * SW + kk];
                gin[rt] = mfma16(aH, c2, gin[rt]);
                ghn[rt] = mfma16(aH, c5, ghn[rt]);
            }
        }
        float Sn = 0.0f;
        #pragma unroll
        for (int rt = 0; rt < 4; rt++)
            #pragma unroll
            for (int i = 0; i < 4; i++) Sn += gin[rt][i];
        Sn += __shfl_xor(Sn, 16); Sn += __shfl_xor(Sn, 32);
        #pragma unroll
        for (int rt = 0; rt < 4; rt++)
            #pragma unroll
            for (int i = 0; i < 4; i++) {
                const int row = rt * 16 + quad * 4 + i;
                const float gi_n = (Sn - gin[rt][i]) * (1.0f / 64.0f) + bin;
                const float rr = bf2f(T0[row * SW + n]);      // own slot
                const float nn = ftanh(gi_n + rr * (ghn[rt][i] + bhn));
                const float z  = zreg[rt][i];
                const float h  = bf2f(T1[row * SW + n]);
                T0[row * SW + n] = f2bf((1.0f - z) * nn + z * h);
            }
    }
    __syncthreads();

    // ---- OUT: out = h' @ W_vd^T + b_vd (val+dec folded) ----
    {
        const int ct = wave & 3;             // 4 col-tiles (H2=64)
        const int rg = wave >> 2;            // 4 row-tiles of 16
        const int nd = ct * 16 + lc;
        const float bias = bvd[nd];
        f32x4 acc = {};
        bf16x8 wc = w8(W_vd, nd * H0 + ko16);
        #pragma unroll 2
        for (int k0 = 0; k0 < H0; k0 += 32) {
            bf16x8 wn = w8(W_vd, nd * H0 + (((k0 + 32) & (H0 - 1)) + ko16));
            const int kk = k0 + ko16;
            bf16x8 a = *(const bf16x8*)&T0[(rg * 16 + lc) * SW + kk];
            acc = mfma16(a, wc, acc);
            wc = wn;
        }
        #pragma unroll
        for (int i = 0; i < 4; i++) {
            const int row = rg * 16 + quad * 4 + i;
            out[(row0 + row) * 64 + nd] = acc[i] + bias;
        }
    }
}

extern "C" void kernel_launch(void* const* d_in, const int* in_sizes, int n_in,
                              void* d_out, int out_size, void* d_ws, size_t ws_size,
                              hipStream_t stream) {
    (void)in_sizes; (void)n_in; (void)out_size; (void)ws_size;
    const float* obs   = (const float*)d_in[0];
    const float* W_enc = (const float*)d_in[1];  const float* b_enc = (const float*)d_in[2];
    const float* W_obs = (const float*)d_in[3];  const float* b_obs = (const float*)d_in[4];
    const float* W_ih  = (const float*)d_in[5];  const float* b_ih  = (const float*)d_in[6];
    const float* W_hh  = (const float*)d_in[7];  const float* b_hh  = (const float*)d_in[8];
    const float* W_val = (const float*)d_in[9];  const float* b_val = (const float*)d_in[10];
    const float* W_dec = (const float*)d_in[11]; const float* b_dec = (const float*)d_in[12];
    float* out = (float*)d_out;
    __hip_bfloat16* ws = (__hip_bfloat16*)d_ws;
    float* bvd = (float*)((char*)d_ws + BVD_BYTE);

    prep_kernel<<<304, 256, 0, stream>>>(W_enc, W_obs, W_ih, W_hh,
                                         W_val, W_dec, b_val, b_dec, ws, bvd);
    commnet_v9<<<256, 1024, 0, stream>>>(ws, bvd, b_enc, b_obs, b_ih, b_hh, obs, out);
}